// Round 15
// baseline (257.451 us; speedup 1.0000x reference)
//
#include <hip/hip_runtime.h>
#include <hip/hip_bf16.h>
#include <math.h>

// ---------------- constants ----------------
#define NP 512
#define NIMG 256
#define NDEL 32
#define NTH 240
#define NINT 250
#define SOS_ELEMS (512*512)
#define MLP_P 32
// swizzled physical index for FFT LDS rows
#define PHY(i) ((i) + ((i) >> 3))
#define RSW 576   // PHY(511)=574 -> row array size
#define PI_F 3.14159265358979323846f

__device__ __forceinline__ int brev9(int i) { return (int)(__brev((unsigned)i) >> 23); }

__device__ __forceinline__ float block_reduce_any(float v) {
  #pragma unroll
  for (int o = 32; o > 0; o >>= 1) v += __shfl_down(v, o, 64);
  __shared__ float red[8];
  int lane = threadIdx.x & 63, wid = threadIdx.x >> 6;
  __syncthreads();
  if (lane == 0) red[wid] = v;
  __syncthreads();
  float r = 0.f;
  if (threadIdx.x == 0) {
    int nw = blockDim.x >> 6;
    for (int i = 0; i < nw; ++i) r += red[i];
  }
  return r;
}

// ---- radix-4 FFT core butterfly (sign = -1 fwd, +1 inv) ----
__device__ __forceinline__ void r4_bfly(float2& x0, float2& x1, float2& x2, float2& x3,
                                        float c1, float s1n, float c2, float s2n, float sign) {
  float t1x = x1.x * c1 - x1.y * s1n, t1y = x1.x * s1n + x1.y * c1;
  float y0x = x0.x + t1x, y0y = x0.y + t1y;
  float y1x = x0.x - t1x, y1y = x0.y - t1y;
  float t3x = x3.x * c1 - x3.y * s1n, t3y = x3.x * s1n + x3.y * c1;
  float y2x = x2.x + t3x, y2y = x2.y + t3y;
  float y3x = x2.x - t3x, y3y = x2.y - t3y;
  float t2x = y2x * c2 - y2y * s2n, t2y = y2x * s2n + y2y * c2;
  float ux = y3x * c2 - y3y * s2n, uy = y3x * s2n + y3y * c2;
  float t4x = -sign * uy, t4y = sign * ux;   // rotate by sign*i (fwd: -i)
  x0 = make_float2(y0x + t2x, y0y + t2y);
  x2 = make_float2(y0x - t2x, y0y - t2y);
  x1 = make_float2(y1x + t4x, y1y + t4y);
  x3 = make_float2(y1x - t4x, y1y - t4y);
}

// radix-4 FFT, 512 pts x 8 rows, 256 threads, swizzled LDS, forward.
__device__ __forceinline__ void fft512_r4_fwd_rows(float2 (*s)[RSW], int tid) {
  #pragma unroll
  for (int pass = 0; pass < 4; ++pass) {
    const int sh = 2 * pass;
    const int h = 1 << sh;
    int p = tid & 127;
    int rbase = (tid >> 7) << 2;
    int j = p & (h - 1);
    int g = p >> sh;
    int base = (g << (sh + 2)) + j;
    int i0 = PHY(base), i1 = PHY(base + h), i2 = PHY(base + 2 * h), i3 = PHY(base + 3 * h);
    float ang1 = -PI_F * (float)j / (float)h;
    float s1n, c1; __sincosf(ang1, &s1n, &c1);
    float s2n, c2; __sincosf(0.5f * ang1, &s2n, &c2);
    #pragma unroll
    for (int rr = 0; rr < 4; ++rr) {
      int r = rbase + rr;
      float2 x0 = s[r][i0], x1 = s[r][i1], x2 = s[r][i2], x3 = s[r][i3];
      r4_bfly(x0, x1, x2, x3, c1, s1n, c2, s2n, -1.f);
      s[r][i0] = x0; s[r][i1] = x1; s[r][i2] = x2; s[r][i3] = x3;
    }
    __syncthreads();
  }
  {
    int p = tid;
    int i1 = PHY(p), i2 = PHY(p + 256);
    float ang = -PI_F * (float)p * (1.f / 256.f);
    float sn, cs; __sincosf(ang, &sn, &cs);
    #pragma unroll
    for (int r = 0; r < 8; ++r) {
      float2 a = s[r][i1], b = s[r][i2];
      float tr = b.x * cs - b.y * sn;
      float ti = b.x * sn + b.y * cs;
      s[r][i1] = make_float2(a.x + tr, a.y + ti);
      s[r][i2] = make_float2(a.x - tr, a.y - ti);
    }
    __syncthreads();
  }
}

// radix-4 FFT, single 512-pt row, 256 threads, swizzled LDS, sign-param.
__device__ __forceinline__ void fft512_r4_row(float2* s, int tid, float sign) {
  #pragma unroll
  for (int pass = 0; pass < 4; ++pass) {
    const int sh = 2 * pass;
    const int h = 1 << sh;
    if (tid < 128) {
      int j = tid & (h - 1);
      int g = tid >> sh;
      int base = (g << (sh + 2)) + j;
      int i0 = PHY(base), i1 = PHY(base + h), i2 = PHY(base + 2 * h), i3 = PHY(base + 3 * h);
      float ang1 = sign * PI_F * (float)j / (float)h;
      float s1n, c1; __sincosf(ang1, &s1n, &c1);
      float s2n, c2; __sincosf(0.5f * ang1, &s2n, &c2);
      float2 x0 = s[i0], x1 = s[i1], x2 = s[i2], x3 = s[i3];
      r4_bfly(x0, x1, x2, x3, c1, s1n, c2, s2n, sign);
      s[i0] = x0; s[i1] = x1; s[i2] = x2; s[i3] = x3;
    }
    __syncthreads();
  }
  {
    int i1 = PHY(tid), i2 = PHY(tid + 256);
    float ang = sign * PI_F * (float)tid * (1.f / 256.f);
    float sn, cs; __sincosf(ang, &sn, &cs);
    float2 a = s[i1], b = s[i2];
    float tr = b.x * cs - b.y * sn;
    float ti = b.x * sn + b.y * cs;
    s[i1] = make_float2(a.x + tr, a.y + ti);
    s[i2] = make_float2(a.x - tr, a.y - ti);
    __syncthreads();
  }
}

// ---------------- K0: init SoS + zero accumulators ----------------
__global__ __launch_bounds__(256) void k_init(float* sos, float* acc) {
  int t = blockIdx.x * 256 + threadIdx.x;
  sos[t] = 1499.363f;
  if (t < 4) acc[t] = 0.f;
}

// ---------------- K1: SIREN MLP + scatter ----------------
// 32 pts/block, 128 threads = 8 pg(4 pts) x 16 jg(8 j split {4jg, 64+4jg}).
// W-chunk = 16 k-rows double-buffered -> 8 staging iters/layer, barriers ~halved.
__global__ __launch_bounds__(128) void k_mlp(
    const float* __restrict__ W1, const float* __restrict__ b1,
    const float* __restrict__ W2, const float* __restrict__ b2,
    const float* __restrict__ W3, const float* __restrict__ b3,
    const float* __restrict__ W4v, const float* __restrict__ b4,
    const float* __restrict__ mgrid, const int* __restrict__ mask_idx,
    int M, float* __restrict__ sos) {
  __shared__ float hbuf[MLP_P][132];
  __shared__ float wbuf[2][16][132];
  __shared__ float xy2[MLP_P][2];
  int tid = threadIdx.x;
  int base = blockIdx.x * MLP_P;
  if (tid < MLP_P * 2) {
    int p = tid >> 1, c = tid & 1;
    float v = 0.f;
    if (base + p < M) v = mgrid[(base + p) * 2 + c];
    xy2[p][c] = v;
  }
  __syncthreads();
  for (int e = tid; e < MLP_P * 128; e += 128) {
    int p = e >> 7, j = e & 127;
    hbuf[p][j] = __sinf(30.f * (xy2[p][0] * W1[j] + xy2[p][1] * W1[128 + j] + b1[j]));
  }
  __syncthreads();

  int jg = tid & 15, pg = tid >> 4;
  int jA = jg * 4, jB = 64 + jg * 4;
  int p0 = pg * 4;
  int wr = tid >> 3, wc = (tid & 7) << 4;   // W staging: 16 rows x 8 thr x 16 floats
  #pragma unroll
  for (int layer = 0; layer < 2; ++layer) {
    const float* Wg = layer ? W3 : W2;
    const float* bb = layer ? b3 : b2;
    float acc[4][8];
    #pragma unroll
    for (int i = 0; i < 4; ++i)
      #pragma unroll
      for (int j = 0; j < 8; ++j) acc[i][j] = 0.f;

    float4 pre[4];
    #pragma unroll
    for (int q = 0; q < 4; ++q)
      pre[q] = *(const float4*)&Wg[wr * 128 + wc + 4 * q];
    for (int c = 0; c < 8; ++c) {
      #pragma unroll
      for (int q = 0; q < 4; ++q)
        *(float4*)&wbuf[c & 1][wr][wc + 4 * q] = pre[q];
      __syncthreads();
      if (c < 7) {
        #pragma unroll
        for (int q = 0; q < 4; ++q)
          pre[q] = *(const float4*)&Wg[((c + 1) * 16 + wr) * 128 + wc + 4 * q];
      }
      #pragma unroll
      for (int half = 0; half < 2; ++half) {
        int k0 = c * 16 + half * 8;
        int wk = half * 8;
        float hreg[4][8];
        #pragma unroll
        for (int i = 0; i < 4; ++i) {
          float4 ha = *(const float4*)&hbuf[p0 + i][k0];
          float4 hb = *(const float4*)&hbuf[p0 + i][k0 + 4];
          hreg[i][0] = ha.x; hreg[i][1] = ha.y; hreg[i][2] = ha.z; hreg[i][3] = ha.w;
          hreg[i][4] = hb.x; hreg[i][5] = hb.y; hreg[i][6] = hb.z; hreg[i][7] = hb.w;
        }
        #pragma unroll
        for (int kk = 0; kk < 8; ++kk) {
          float4 wa = *(const float4*)&wbuf[c & 1][wk + kk][jA];
          float4 wb = *(const float4*)&wbuf[c & 1][wk + kk][jB];
          float w8[8] = {wa.x, wa.y, wa.z, wa.w, wb.x, wb.y, wb.z, wb.w};
          #pragma unroll
          for (int i = 0; i < 4; ++i) {
            float hv = hreg[i][kk];
            #pragma unroll
            for (int j = 0; j < 8; ++j) acc[i][j] += hv * w8[j];
          }
        }
      }
    }
    float breg[8];
    #pragma unroll
    for (int j = 0; j < 4; ++j) { breg[j] = bb[jA + j]; breg[4 + j] = bb[jB + j]; }
    __syncthreads();
    #pragma unroll
    for (int i = 0; i < 4; ++i) {
      float o[8];
      #pragma unroll
      for (int j = 0; j < 8; ++j) o[j] = __sinf(30.f * (acc[i][j] + breg[j]));
      *(float4*)&hbuf[p0 + i][jA] = make_float4(o[0], o[1], o[2], o[3]);
      *(float4*)&hbuf[p0 + i][jB] = make_float4(o[4], o[5], o[6], o[7]);
    }
    __syncthreads();
  }
  {
    int p = tid >> 2, q = tid & 3;
    float s = 0.f;
    #pragma unroll
    for (int k = 0; k < 32; k += 4) {
      float4 h4 = *(const float4*)&hbuf[p][q * 32 + k];
      float4 w4 = *(const float4*)&W4v[q * 32 + k];
      s += h4.x * w4.x + h4.y * w4.y + h4.z * w4.z + h4.w * w4.w;
    }
    s += __shfl_down(s, 1, 64);
    s += __shfl_down(s, 2, 64);
    if (q == 0 && base + p < M)
      sos[mask_idx[base + p]] = (s + b4[0]) * 170.f + 1550.f;
  }
}

// ---------------- K2: wavefront ray integrals ----------------
__global__ __launch_bounds__(256) void k_wavefront(
    const float* __restrict__ sos, const float* __restrict__ xq_p,
    const float* __restrict__ yq_p, const float* __restrict__ x_vec,
    const float* __restrict__ y_vec, float* __restrict__ wfs) {
  int i = blockIdx.x;
  int j = threadIdx.x;
  float xq = xq_p[0], yq = yq_p[0];
  float r = sqrtf(xq * xq + yq * yq);
  float phi = atan2f(xq, yq);
  float th = (float)((double)i * (2.0 * M_PI / 239.0));
  float s = sinf(th - phi), cd = cosf(th - phi);
  const float R2 = 0.008f * 0.008f;
  float disc = fmaxf(R2 - (r * s) * (r * s), 0.f);
  float sq = sqrtf(disc);
  float l_in = sq + r * cd;
  float l_out = 2.f * sq * (cd >= 0.f ? 1.f : 0.f);
  float l = (r < 0.008f) ? l_in : l_out;
  float x0 = x_vec[0], dx = x_vec[1] - x_vec[0];
  float y0 = y_vec[0], dy = y_vec[1] - y_vec[0];
  float sinth = sinf(th), costh = cosf(th);
  float contrib = 0.f;
  if (j < NINT) {
    float sj = (float)j * (1.f / 249.f);
    int xi = (int)rintf((xq - l * sj * sinth - x0) / dx);
    int yi = (int)rintf((yq - l * sj * costh - y0) / dy);
    float sv = sos[(((-yi) & 511) << 9) + (xi & 511)];
    float f = 1.f - 1500.f / sv;
    float wgt = (j == 0 || j == NINT - 1) ? 0.5f : 1.f;
    contrib = wgt * f;
  }
  float tot = block_reduce_any(contrib);
  if (threadIdx.x == 0) wfs[i] = tot * l * (1.f / 249.f);
}

// ---------------- K3: windowed v-axis FFT (radix-4), transposed store ------
// Hermitian: only v=0..256 rows are stored (Y(-u,-v)=conj Y(u,v)).
__global__ __launch_bounds__(256) void k_fwdT(const float* __restrict__ y_img,
                                              float2* __restrict__ bufA) {
  __shared__ float2 s[8][RSW];
  int rt = blockIdx.x;
  int d = blockIdx.y;
  int tid = threadIdx.x;
  const float INV2S2 = (float)(0.6931471805599453 / 1406.25);
  for (int e = tid; e < 2048; e += 256) {
    int i = e >> 8, c = e & 255;
    int r = rt * 8 + i;
    float axr = (float)r - 127.5f;
    float axc = (float)c - 127.5f;
    float g = __expf(-(axr * axr + axc * axc) * INV2S2);
    float val = y_img[((size_t)d << 16) + (r << 8) + c] * g;
    s[i][PHY(brev9((c + 384) & 511))] = make_float2(val, 0.f);
    s[i][PHY(brev9(c + 128))] = make_float2(0.f, 0.f);
  }
  __syncthreads();
  fft512_r4_fwd_rows(s, tid);
  float2* outp = bufA + ((size_t)d << 17) + rt * 8;
  for (int e = tid; e < 2056; e += 256) {   // 257 v-rows x 8
    int i = e & 7, v = e >> 3;
    outp[(size_t)v * 256 + i] = s[i][PHY(v)];
  }
}

// ---------------- K4: u-axis FFT + deconv + loss + u-axis ifft of X --------
// Hermitian-halved: grid = 257 v-blocks; loss weight 2 for v in [1,255];
// mirror store X(512-v) = conj(X(v)) after the u-ifft.
__device__ __forceinline__ float interp_wf(const float* wfs, float xn) {
  const float dxg = (float)(2.0 * M_PI / 239.0);
  float t = xn / dxg;
  int f = (int)floorf(t); f = min(max(f, 0), 239);
  int c = (int)ceilf(t);  c = min(max(c, 0), 239);
  float yf = wfs[f], yc = wfs[c];
  if (c == f) return yc;
  float xgf = (float)f * dxg;
  return yf + (yc - yf) * (xn - xgf) / ((float)(c - f) * dxg);
}

__global__ __launch_bounds__(256) void k_colfft_deconv(
    const float2* __restrict__ bufA, const float* __restrict__ delays,
    const float* __restrict__ wfs_g, float2* __restrict__ Xo,
    float* __restrict__ acc) {
  __shared__ float2 s[8][RSW];
  __shared__ float wfs[NTH];
  __shared__ float dly[NDEL];
  int v = blockIdx.x;            // 0..256
  int tid = threadIdx.x;
  if (tid < NTH) wfs[tid] = wfs_g[tid];
  if (tid < NDEL) dly[tid] = delays[tid];
  __syncthreads();

  const float inv_nd = 1.f / 0.02048f;
  const float TWO_PI = 6.28318530717958647692f;
  float fy = (float)(v < 256 ? v : v - 512) * inv_nd;
  float kkA[2];
  float2 zw[2], zwpi[2];   // exp(i kk w), exp(i kk wpi)
  int up[2];
  #pragma unroll
  for (int uu = 0; uu < 2; ++uu) {
    int u = tid + 256 * uu;
    up[uu] = PHY(u);
    float fx = (float)(u < 256 ? u : u - 512) * inv_nd;
    float kk = TWO_PI * sqrtf(fx * fx + fy * fy);
    kkA[uu] = kk;
    float th = atan2f(fy, fx);
    if (th < 0.f) th += TWO_PI;
    float w = interp_wf(wfs, th);
    float thpi = th + PI_F;
    if (thpi >= TWO_PI) thpi -= TWO_PI;
    float wpi = interp_wf(wfs, thpi);
    float snw, csw; __sincosf(kk * w, &snw, &csw);
    zw[uu] = make_float2(csw, snw);
    float snp, csp; __sincosf(kk * wpi, &snp, &csp);
    zwpi[uu] = make_float2(csp, snp);
  }

  float rhsr[2] = {0.f, 0.f}, rhsi[2] = {0.f, 0.f}, lhs[2] = {0.f, 0.f};
  float sY2[2] = {0.f, 0.f}, sYH[2] = {0.f, 0.f};

  for (int c4 = 0; c4 < 4; ++c4) {
    __syncthreads();   // previous chunk's reads done
    for (int e = tid; e < 2048; e += 256) {
      int ch = e >> 8, c = e & 255;
      float2 val = bufA[((size_t)(c4 * 8 + ch) << 17) + (size_t)v * 256 + c];
      s[ch][PHY(brev9((c + 384) & 511))] = val;
      s[ch][PHY(brev9(c + 128))] = make_float2(0.f, 0.f);
    }
    __syncthreads();
    fft512_r4_fwd_rows(s, tid);
    #pragma unroll
    for (int uu = 0; uu < 2; ++uu) {
      float kk = kkA[uu];
      float2 w0 = zw[uu], w1 = zwpi[uu];
      #pragma unroll
      for (int ch = 0; ch < 8; ++ch) {
        float dl = dly[c4 * 8 + ch];
        float sd, cd2;
        __sincosf(kk * dl, &sd, &cd2);
        // H = 0.5*(conj(zd)*zw + zd*conj(zwpi)), zd = exp(i kk d)
        float t0r = cd2 * w0.x + sd * w0.y;
        float t0i = cd2 * w0.y - sd * w0.x;
        float t1r = cd2 * w1.x + sd * w1.y;
        float t1i = sd * w1.x - cd2 * w1.y;
        float Hr = 0.5f * (t0r + t1r);
        float Hi = 0.5f * (t0i + t1i);
        float2 Yv = s[ch][up[uu]];
        rhsr[uu] += Yv.x * Hr + Yv.y * Hi;
        rhsi[uu] += Yv.y * Hr - Yv.x * Hi;
        float h2 = Hr * Hr + Hi * Hi;
        float y2 = Yv.x * Yv.x + Yv.y * Yv.y;
        lhs[uu] += h2;
        sY2[uu] += y2;
        sYH[uu] += sqrtf(y2 * h2);
      }
    }
  }
  // finalize X (registers) + weighted loss (Hermitian doubling)
  float lw = (v == 0 || v == 256) ? 1.f : 2.f;
  float2 Xv[2];
  float lsum = 0.f;
  #pragma unroll
  for (int uu = 0; uu < 2; ++uu) {
    float Xr = rhsr[uu] / lhs[uu], Xi = rhsi[uu] / lhs[uu];
    Xv[uu] = make_float2(Xr, Xi);
    float aX = sqrtf(Xr * Xr + Xi * Xi);
    float kk2 = kkA[uu] * kkA[uu];
    lsum += kk2 * (sY2[uu] - 2.f * aX * sYH[uu] + aX * aX * lhs[uu]);
  }
  float bs = block_reduce_any(lsum * lw);
  if (threadIdx.x == 0) atomicAdd(&acc[0], bs);
  // fused u-axis inverse FFT of this v's X row (reuse LDS row 0)
  __syncthreads();
  float2* s0 = &s[0][0];
  s0[PHY(brev9(tid))] = Xv[0];
  s0[PHY(brev9(tid + 256))] = Xv[1];
  __syncthreads();
  fft512_r4_row(s0, tid, +1.f);
  const float sc = 1.f / 512.f;
  float2 o0 = s0[PHY(tid)], o1 = s0[PHY(tid + 256)];
  o0.x *= sc; o0.y *= sc; o1.x *= sc; o1.y *= sc;
  Xo[((size_t)v << 9) + tid] = o0;
  Xo[((size_t)v << 9) + tid + 256] = o1;
  if (v != 0 && v != 256) {
    int vm = 512 - v;
    Xo[((size_t)vm << 9) + tid] = make_float2(o0.x, -o0.y);
    Xo[((size_t)vm << 9) + tid + 256] = make_float2(o1.x, -o1.y);
  }
}

// ---------------- K5: in-place paired-tile transpose ----------------
__global__ __launch_bounds__(256) void k_transpose_ip(float2* __restrict__ B) {
  int ti = blockIdx.x, tj = blockIdx.y;
  if (ti > tj) return;
  __shared__ float2 At[32][33];
  __shared__ float2 Bt[32][33];
  int tid = threadIdx.x;
  for (int e = tid; e < 1024; e += 256) {
    int r = e >> 5, c = e & 31;
    At[r][c] = B[(size_t)(ti * 32 + r) * 512 + tj * 32 + c];
    if (ti != tj) Bt[r][c] = B[(size_t)(tj * 32 + r) * 512 + ti * 32 + c];
  }
  __syncthreads();
  for (int e = tid; e < 1024; e += 256) {
    int r = e >> 5, c = e & 31;
    B[(size_t)(tj * 32 + r) * 512 + ti * 32 + c] = At[c][r];
    if (ti != tj) B[(size_t)(ti * 32 + r) * 512 + tj * 32 + c] = Bt[c][r];
  }
}

// ---------------- K6: final inverse row FFT (radix-4) + fftshift store -----
__global__ __launch_bounds__(256) void k_final_rows(const float2* __restrict__ buf,
                                                    float* __restrict__ xrec) {
  __shared__ float2 s[RSW];
  int arow = blockIdx.x;
  const float2* p = buf + ((size_t)arow << 9);
  int tid = threadIdx.x;
  s[PHY(brev9(tid))] = p[tid];
  s[PHY(brev9(tid + 256))] = p[tid + 256];
  __syncthreads();
  fft512_r4_row(s, tid, +1.f);
  int orow = (arow + 256) & 511;
  const float sc = 1.f / 512.f;
  xrec[(orow << 9) + ((tid + 256) & 511)] = s[PHY(tid)].x * sc;
  xrec[(orow << 9) + (tid & 511)] = s[PHY(tid + 256)].x * sc;
}

// ---------------- K7: TV + L1 reductions (atomics only, NO fence) ----------
__global__ __launch_bounds__(256) void k_tvl1(const float* __restrict__ sos,
                                              const float* __restrict__ mask,
                                              float* __restrict__ acc) {
  int t = blockIdx.x * 256 + threadIdx.x;
  float s = sos[t];
  float m = mask[t];
  int i = t >> 9, j = t & 511;
  float tv = 0.f;
  if (i > 0) tv += fabsf((s - sos[t - 512]) * m);
  if (j > 0) tv += fabsf((s - sos[t - 1]) * m);
  float l1 = fabsf(s - 1550.f) * m;
  float tvb = block_reduce_any(tv);
  float l1b = block_reduce_any(l1);
  if (threadIdx.x == 0) {
    atomicAdd(&acc[1], tvb);
    atomicAdd(&acc[2], l1b);
  }
}

// ---------------- K8: finalize loss (separate launch = ordering) ----------
__global__ void k_finalize(const float* __restrict__ acc, float* __restrict__ out) {
  out[0] = acc[0] * (1.f / 8388608.f) + 1e-3f * acc[1] + 1e-3f * (acc[2] * (1.f / 262144.f));
}

// ---------------- launch ----------------
extern "C" void kernel_launch(void* const* d_in, const int* in_sizes, int n_in,
                              void* d_out, int out_size, void* d_ws, size_t ws_size,
                              hipStream_t stream) {
  const float* W1 = (const float*)d_in[0];
  const float* b1 = (const float*)d_in[1];
  const float* W2 = (const float*)d_in[2];
  const float* b2 = (const float*)d_in[3];
  const float* W3 = (const float*)d_in[4];
  const float* b3 = (const float*)d_in[5];
  const float* W4 = (const float*)d_in[6];
  const float* b4 = (const float*)d_in[7];
  const float* y_img = (const float*)d_in[8];
  const float* delays = (const float*)d_in[9];
  const float* xq = (const float*)d_in[10];
  const float* yq = (const float*)d_in[11];
  const float* mgrid = (const float*)d_in[12];
  const float* mask = (const float*)d_in[13];
  const int* mask_idx = (const int*)d_in[14];
  const float* x_vec = (const float*)d_in[15];
  const float* y_vec = (const float*)d_in[16];
  const int M = in_sizes[14];
  const int nMlp = (M + MLP_P - 1) / MLP_P;

  float* out = (float*)d_out;
  float* xrec = out;                    // 262144
  float* sos = out + SOS_ELEMS;         // 262144
  float* loss = out + 2 * SOS_ELEMS;    // 1

  char* wsb = (char*)d_ws;
  float* acc = (float*)wsb;                                     // 4 floats
  float* wfs = (float*)(wsb + 1024);                            // 240 floats
  float2* bufA = (float2*)(wsb + 4096);                         // 32*512*257 c64
  float2* bufX = (float2*)(wsb + 4096 + (size_t)NDEL * 512 * 256 * sizeof(float2)); // 2 MB

  k_init<<<1024, 256, 0, stream>>>(sos, acc);
  k_mlp<<<nMlp, 128, 0, stream>>>(W1, b1, W2, b2, W3, b3, W4, b4,
                                  mgrid, mask_idx, M, sos);
  k_wavefront<<<NTH, 256, 0, stream>>>(sos, xq, yq, x_vec, y_vec, wfs);
  k_fwdT<<<dim3(32, NDEL), 256, 0, stream>>>(y_img, bufA);
  k_colfft_deconv<<<257, 256, 0, stream>>>(bufA, delays, wfs, bufX, acc); // Hermitian half
  k_transpose_ip<<<dim3(16, 16), 256, 0, stream>>>(bufX);
  k_final_rows<<<512, 256, 0, stream>>>(bufX, xrec);
  k_tvl1<<<1024, 256, 0, stream>>>(sos, mask, acc);
  k_finalize<<<1, 1, 0, stream>>>(acc, loss);
}

// Round 16
// 222.946 us; speedup vs baseline: 1.1548x; 1.1548x over previous
//
#include <hip/hip_runtime.h>
#include <hip/hip_bf16.h>
#include <math.h>

// ---------------- constants ----------------
#define NP 512
#define NIMG 256
#define NDEL 32
#define NTH 240
#define NINT 250
#define SOS_ELEMS (512*512)
#define MLP_P 32
// swizzled physical index for FFT LDS rows
#define PHY(i) ((i) + ((i) >> 3))
#define RSW 576   // PHY(511)=574 -> row array size
#define PI_F 3.14159265358979323846f

__device__ __forceinline__ int brev9(int i) { return (int)(__brev((unsigned)i) >> 23); }

__device__ __forceinline__ float block_reduce_any(float v) {
  #pragma unroll
  for (int o = 32; o > 0; o >>= 1) v += __shfl_down(v, o, 64);
  __shared__ float red[8];
  int lane = threadIdx.x & 63, wid = threadIdx.x >> 6;
  __syncthreads();
  if (lane == 0) red[wid] = v;
  __syncthreads();
  float r = 0.f;
  if (threadIdx.x == 0) {
    int nw = blockDim.x >> 6;
    for (int i = 0; i < nw; ++i) r += red[i];
  }
  return r;
}

// ---- radix-4 FFT core butterfly (sign = -1 fwd, +1 inv) ----
__device__ __forceinline__ void r4_bfly(float2& x0, float2& x1, float2& x2, float2& x3,
                                        float c1, float s1n, float c2, float s2n, float sign) {
  float t1x = x1.x * c1 - x1.y * s1n, t1y = x1.x * s1n + x1.y * c1;
  float y0x = x0.x + t1x, y0y = x0.y + t1y;
  float y1x = x0.x - t1x, y1y = x0.y - t1y;
  float t3x = x3.x * c1 - x3.y * s1n, t3y = x3.x * s1n + x3.y * c1;
  float y2x = x2.x + t3x, y2y = x2.y + t3y;
  float y3x = x2.x - t3x, y3y = x2.y - t3y;
  float t2x = y2x * c2 - y2y * s2n, t2y = y2x * s2n + y2y * c2;
  float ux = y3x * c2 - y3y * s2n, uy = y3x * s2n + y3y * c2;
  float t4x = -sign * uy, t4y = sign * ux;   // rotate by sign*i (fwd: -i)
  x0 = make_float2(y0x + t2x, y0y + t2y);
  x2 = make_float2(y0x - t2x, y0y - t2y);
  x1 = make_float2(y1x + t4x, y1y + t4y);
  x3 = make_float2(y1x - t4x, y1y - t4y);
}

// radix-4 FFT, 512 pts x 8 rows, 256 threads, swizzled LDS, forward.
__device__ __forceinline__ void fft512_r4_fwd_rows(float2 (*s)[RSW], int tid) {
  #pragma unroll
  for (int pass = 0; pass < 4; ++pass) {
    const int sh = 2 * pass;
    const int h = 1 << sh;
    int p = tid & 127;
    int rbase = (tid >> 7) << 2;
    int j = p & (h - 1);
    int g = p >> sh;
    int base = (g << (sh + 2)) + j;
    int i0 = PHY(base), i1 = PHY(base + h), i2 = PHY(base + 2 * h), i3 = PHY(base + 3 * h);
    float ang1 = -PI_F * (float)j / (float)h;
    float s1n, c1; __sincosf(ang1, &s1n, &c1);
    float s2n, c2; __sincosf(0.5f * ang1, &s2n, &c2);
    #pragma unroll
    for (int rr = 0; rr < 4; ++rr) {
      int r = rbase + rr;
      float2 x0 = s[r][i0], x1 = s[r][i1], x2 = s[r][i2], x3 = s[r][i3];
      r4_bfly(x0, x1, x2, x3, c1, s1n, c2, s2n, -1.f);
      s[r][i0] = x0; s[r][i1] = x1; s[r][i2] = x2; s[r][i3] = x3;
    }
    __syncthreads();
  }
  {
    int p = tid;
    int i1 = PHY(p), i2 = PHY(p + 256);
    float ang = -PI_F * (float)p * (1.f / 256.f);
    float sn, cs; __sincosf(ang, &sn, &cs);
    #pragma unroll
    for (int r = 0; r < 8; ++r) {
      float2 a = s[r][i1], b = s[r][i2];
      float tr = b.x * cs - b.y * sn;
      float ti = b.x * sn + b.y * cs;
      s[r][i1] = make_float2(a.x + tr, a.y + ti);
      s[r][i2] = make_float2(a.x - tr, a.y - ti);
    }
    __syncthreads();
  }
}

// radix-4 FFT, 512 pts x 4 rows (packed real pairs), 256 threads.
__device__ __forceinline__ void fft512_r4_fwd_rows4(float2 (*s)[RSW], int tid) {
  #pragma unroll
  for (int pass = 0; pass < 4; ++pass) {
    const int sh = 2 * pass;
    const int h = 1 << sh;
    int p = tid & 127;
    int rbase = (tid >> 7) << 1;
    int j = p & (h - 1);
    int g = p >> sh;
    int base = (g << (sh + 2)) + j;
    int i0 = PHY(base), i1 = PHY(base + h), i2 = PHY(base + 2 * h), i3 = PHY(base + 3 * h);
    float ang1 = -PI_F * (float)j / (float)h;
    float s1n, c1; __sincosf(ang1, &s1n, &c1);
    float s2n, c2; __sincosf(0.5f * ang1, &s2n, &c2);
    #pragma unroll
    for (int rr = 0; rr < 2; ++rr) {
      int r = rbase + rr;
      float2 x0 = s[r][i0], x1 = s[r][i1], x2 = s[r][i2], x3 = s[r][i3];
      r4_bfly(x0, x1, x2, x3, c1, s1n, c2, s2n, -1.f);
      s[r][i0] = x0; s[r][i1] = x1; s[r][i2] = x2; s[r][i3] = x3;
    }
    __syncthreads();
  }
  {
    int p = tid;
    int i1 = PHY(p), i2 = PHY(p + 256);
    float ang = -PI_F * (float)p * (1.f / 256.f);
    float sn, cs; __sincosf(ang, &sn, &cs);
    #pragma unroll
    for (int r = 0; r < 4; ++r) {
      float2 a = s[r][i1], b = s[r][i2];
      float tr = b.x * cs - b.y * sn;
      float ti = b.x * sn + b.y * cs;
      s[r][i1] = make_float2(a.x + tr, a.y + ti);
      s[r][i2] = make_float2(a.x - tr, a.y - ti);
    }
    __syncthreads();
  }
}

// radix-4 FFT, single 512-pt row, 256 threads, swizzled LDS, sign-param.
__device__ __forceinline__ void fft512_r4_row(float2* s, int tid, float sign) {
  #pragma unroll
  for (int pass = 0; pass < 4; ++pass) {
    const int sh = 2 * pass;
    const int h = 1 << sh;
    if (tid < 128) {
      int j = tid & (h - 1);
      int g = tid >> sh;
      int base = (g << (sh + 2)) + j;
      int i0 = PHY(base), i1 = PHY(base + h), i2 = PHY(base + 2 * h), i3 = PHY(base + 3 * h);
      float ang1 = sign * PI_F * (float)j / (float)h;
      float s1n, c1; __sincosf(ang1, &s1n, &c1);
      float s2n, c2; __sincosf(0.5f * ang1, &s2n, &c2);
      float2 x0 = s[i0], x1 = s[i1], x2 = s[i2], x3 = s[i3];
      r4_bfly(x0, x1, x2, x3, c1, s1n, c2, s2n, sign);
      s[i0] = x0; s[i1] = x1; s[i2] = x2; s[i3] = x3;
    }
    __syncthreads();
  }
  {
    int i1 = PHY(tid), i2 = PHY(tid + 256);
    float ang = sign * PI_F * (float)tid * (1.f / 256.f);
    float sn, cs; __sincosf(ang, &sn, &cs);
    float2 a = s[i1], b = s[i2];
    float tr = b.x * cs - b.y * sn;
    float ti = b.x * sn + b.y * cs;
    s[i1] = make_float2(a.x + tr, a.y + ti);
    s[i2] = make_float2(a.x - tr, a.y - ti);
    __syncthreads();
  }
}

// ---------------- K0: init SoS + zero accumulators ----------------
__global__ __launch_bounds__(256) void k_init(float* sos, float* acc) {
  int t = blockIdx.x * 256 + threadIdx.x;
  sos[t] = 1499.363f;
  if (t < 4) acc[t] = 0.f;
}

// ---------------- K1: SIREN MLP + scatter (R14-measured 46.5 us, VGPR 84) --
// 32 pts/block, 128 threads = 8 pg(4 pts) x 16 jg(8 j split {4jg, 64+4jg}).
// DO NOT retile: R10 split / R11 shrink / R15 16-row wbuf all regressed.
__global__ __launch_bounds__(128) void k_mlp(
    const float* __restrict__ W1, const float* __restrict__ b1,
    const float* __restrict__ W2, const float* __restrict__ b2,
    const float* __restrict__ W3, const float* __restrict__ b3,
    const float* __restrict__ W4v, const float* __restrict__ b4,
    const float* __restrict__ mgrid, const int* __restrict__ mask_idx,
    int M, float* __restrict__ sos) {
  __shared__ float hbuf[MLP_P][132];
  __shared__ float wbuf[2][8][132];
  __shared__ float xy2[MLP_P][2];
  int tid = threadIdx.x;
  int base = blockIdx.x * MLP_P;
  if (tid < MLP_P * 2) {
    int p = tid >> 1, c = tid & 1;
    float v = 0.f;
    if (base + p < M) v = mgrid[(base + p) * 2 + c];
    xy2[p][c] = v;
  }
  __syncthreads();
  for (int e = tid; e < MLP_P * 128; e += 128) {
    int p = e >> 7, j = e & 127;
    hbuf[p][j] = __sinf(30.f * (xy2[p][0] * W1[j] + xy2[p][1] * W1[128 + j] + b1[j]));
  }
  __syncthreads();

  int jg = tid & 15, pg = tid >> 4;
  int jA = jg * 4, jB = 64 + jg * 4;
  int p0 = pg * 4;
  int wr = tid >> 4, wc = (tid & 15) << 3;
  #pragma unroll
  for (int layer = 0; layer < 2; ++layer) {
    const float* Wg = layer ? W3 : W2;
    const float* bb = layer ? b3 : b2;
    float acc[4][8];
    #pragma unroll
    for (int i = 0; i < 4; ++i)
      #pragma unroll
      for (int j = 0; j < 8; ++j) acc[i][j] = 0.f;

    float4 pre1 = *(const float4*)&Wg[wr * 128 + wc];
    float4 pre2 = *(const float4*)&Wg[wr * 128 + wc + 4];
    for (int c = 0; c < 16; ++c) {
      *(float4*)&wbuf[c & 1][wr][wc] = pre1;
      *(float4*)&wbuf[c & 1][wr][wc + 4] = pre2;
      __syncthreads();
      if (c < 15) {
        pre1 = *(const float4*)&Wg[((c + 1) * 8 + wr) * 128 + wc];
        pre2 = *(const float4*)&Wg[((c + 1) * 8 + wr) * 128 + wc + 4];
      }
      int k0 = c * 8;
      float hreg[4][8];
      #pragma unroll
      for (int i = 0; i < 4; ++i) {
        float4 ha = *(const float4*)&hbuf[p0 + i][k0];
        float4 hb = *(const float4*)&hbuf[p0 + i][k0 + 4];
        hreg[i][0] = ha.x; hreg[i][1] = ha.y; hreg[i][2] = ha.z; hreg[i][3] = ha.w;
        hreg[i][4] = hb.x; hreg[i][5] = hb.y; hreg[i][6] = hb.z; hreg[i][7] = hb.w;
      }
      #pragma unroll
      for (int kk = 0; kk < 8; ++kk) {
        float4 wa = *(const float4*)&wbuf[c & 1][kk][jA];
        float4 wb = *(const float4*)&wbuf[c & 1][kk][jB];
        float w8[8] = {wa.x, wa.y, wa.z, wa.w, wb.x, wb.y, wb.z, wb.w};
        #pragma unroll
        for (int i = 0; i < 4; ++i) {
          float hv = hreg[i][kk];
          #pragma unroll
          for (int j = 0; j < 8; ++j) acc[i][j] += hv * w8[j];
        }
      }
    }
    float breg[8];
    #pragma unroll
    for (int j = 0; j < 4; ++j) { breg[j] = bb[jA + j]; breg[4 + j] = bb[jB + j]; }
    __syncthreads();
    #pragma unroll
    for (int i = 0; i < 4; ++i) {
      float o[8];
      #pragma unroll
      for (int j = 0; j < 8; ++j) o[j] = __sinf(30.f * (acc[i][j] + breg[j]));
      *(float4*)&hbuf[p0 + i][jA] = make_float4(o[0], o[1], o[2], o[3]);
      *(float4*)&hbuf[p0 + i][jB] = make_float4(o[4], o[5], o[6], o[7]);
    }
    __syncthreads();
  }
  {
    int p = tid >> 2, q = tid & 3;
    float s = 0.f;
    #pragma unroll
    for (int k = 0; k < 32; k += 4) {
      float4 h4 = *(const float4*)&hbuf[p][q * 32 + k];
      float4 w4 = *(const float4*)&W4v[q * 32 + k];
      s += h4.x * w4.x + h4.y * w4.y + h4.z * w4.z + h4.w * w4.w;
    }
    s += __shfl_down(s, 1, 64);
    s += __shfl_down(s, 2, 64);
    if (q == 0 && base + p < M)
      sos[mask_idx[base + p]] = (s + b4[0]) * 170.f + 1550.f;
  }
}

// ---------------- K2: wavefront ray integrals ----------------
__global__ __launch_bounds__(256) void k_wavefront(
    const float* __restrict__ sos, const float* __restrict__ xq_p,
    const float* __restrict__ yq_p, const float* __restrict__ x_vec,
    const float* __restrict__ y_vec, float* __restrict__ wfs) {
  int i = blockIdx.x;
  int j = threadIdx.x;
  float xq = xq_p[0], yq = yq_p[0];
  float r = sqrtf(xq * xq + yq * yq);
  float phi = atan2f(xq, yq);
  float th = (float)((double)i * (2.0 * M_PI / 239.0));
  float s = sinf(th - phi), cd = cosf(th - phi);
  const float R2 = 0.008f * 0.008f;
  float disc = fmaxf(R2 - (r * s) * (r * s), 0.f);
  float sq = sqrtf(disc);
  float l_in = sq + r * cd;
  float l_out = 2.f * sq * (cd >= 0.f ? 1.f : 0.f);
  float l = (r < 0.008f) ? l_in : l_out;
  float x0 = x_vec[0], dx = x_vec[1] - x_vec[0];
  float y0 = y_vec[0], dy = y_vec[1] - y_vec[0];
  float sinth = sinf(th), costh = cosf(th);
  float contrib = 0.f;
  if (j < NINT) {
    float sj = (float)j * (1.f / 249.f);
    int xi = (int)rintf((xq - l * sj * sinth - x0) / dx);
    int yi = (int)rintf((yq - l * sj * costh - y0) / dy);
    float sv = sos[(((-yi) & 511) << 9) + (xi & 511)];
    float f = 1.f - 1500.f / sv;
    float wgt = (j == 0 || j == NINT - 1) ? 0.5f : 1.f;
    contrib = wgt * f;
  }
  float tot = block_reduce_any(contrib);
  if (threadIdx.x == 0) wfs[i] = tot * l * (1.f / 249.f);
}

// ---------------- K3: windowed v-axis FFT, REAL-PAIR packed (4 FFTs/block) -
// z = row_a + i*row_b; Y_a=(Z(v)+conj(Z(-v)))/2, Y_b=-i(Z(v)-conj(Z(-v)))/2.
// Hermitian: only v=0..256 rows stored.
__global__ __launch_bounds__(256) void k_fwdT(const float* __restrict__ y_img,
                                              float2* __restrict__ bufA) {
  __shared__ float2 s[4][RSW];
  int rt = blockIdx.x;
  int d = blockIdx.y;
  int tid = threadIdx.x;
  const float INV2S2 = (float)(0.6931471805599453 / 1406.25);
  for (int e = tid; e < 2048; e += 256) {
    int i = e >> 8, c = e & 255;
    int r = rt * 8 + i;
    float axr = (float)r - 127.5f;
    float axc = (float)c - 127.5f;
    float g = __expf(-(axr * axr + axc * axc) * INV2S2);
    float val = y_img[((size_t)d << 16) + (r << 8) + c] * g;
    int p = i >> 1, comp = i & 1;
    ((float*)&s[p][PHY(brev9((c + 384) & 511))])[comp] = val;
    ((float*)&s[p][PHY(brev9(c + 128))])[comp] = 0.f;
  }
  __syncthreads();
  fft512_r4_fwd_rows4(s, tid);
  float2* outp = bufA + ((size_t)d << 17) + rt * 8;
  for (int e = tid; e < 2056; e += 256) {   // 257 v-rows x 8
    int i = e & 7, v = e >> 3;
    int p = i >> 1, comp = i & 1;
    float2 Zv = s[p][PHY(v)];
    float2 Zm = s[p][PHY((512 - v) & 511)];
    float2 Yv;
    if (comp == 0) Yv = make_float2(0.5f * (Zv.x + Zm.x), 0.5f * (Zv.y - Zm.y));
    else           Yv = make_float2(0.5f * (Zv.y + Zm.y), 0.5f * (Zm.x - Zv.x));
    outp[(size_t)v * 256 + i] = Yv;
  }
}

// ---------------- K4: u-axis FFT + deconv + loss + u-axis ifft of X --------
// Hermitian-halved: grid = 257 v-blocks; loss weight 2 for v in [1,255];
// mirror store X(512-v) = conj(X(v)) after the u-ifft.
__device__ __forceinline__ float interp_wf(const float* wfs, float xn) {
  const float dxg = (float)(2.0 * M_PI / 239.0);
  float t = xn / dxg;
  int f = (int)floorf(t); f = min(max(f, 0), 239);
  int c = (int)ceilf(t);  c = min(max(c, 0), 239);
  float yf = wfs[f], yc = wfs[c];
  if (c == f) return yc;
  float xgf = (float)f * dxg;
  return yf + (yc - yf) * (xn - xgf) / ((float)(c - f) * dxg);
}

__global__ __launch_bounds__(256) void k_colfft_deconv(
    const float2* __restrict__ bufA, const float* __restrict__ delays,
    const float* __restrict__ wfs_g, float2* __restrict__ Xo,
    float* __restrict__ acc) {
  __shared__ float2 s[8][RSW];
  __shared__ float wfs[NTH];
  __shared__ float dly[NDEL];
  int v = blockIdx.x;            // 0..256
  int tid = threadIdx.x;
  if (tid < NTH) wfs[tid] = wfs_g[tid];
  if (tid < NDEL) dly[tid] = delays[tid];
  __syncthreads();

  const float inv_nd = 1.f / 0.02048f;
  const float TWO_PI = 6.28318530717958647692f;
  float fy = (float)(v < 256 ? v : v - 512) * inv_nd;
  float kkA[2];
  float2 zw[2], zwpi[2];   // exp(i kk w), exp(i kk wpi)
  int up[2];
  #pragma unroll
  for (int uu = 0; uu < 2; ++uu) {
    int u = tid + 256 * uu;
    up[uu] = PHY(u);
    float fx = (float)(u < 256 ? u : u - 512) * inv_nd;
    float kk = TWO_PI * sqrtf(fx * fx + fy * fy);
    kkA[uu] = kk;
    float th = atan2f(fy, fx);
    if (th < 0.f) th += TWO_PI;
    float w = interp_wf(wfs, th);
    float thpi = th + PI_F;
    if (thpi >= TWO_PI) thpi -= TWO_PI;
    float wpi = interp_wf(wfs, thpi);
    float snw, csw; __sincosf(kk * w, &snw, &csw);
    zw[uu] = make_float2(csw, snw);
    float snp, csp; __sincosf(kk * wpi, &snp, &csp);
    zwpi[uu] = make_float2(csp, snp);
  }

  float rhsr[2] = {0.f, 0.f}, rhsi[2] = {0.f, 0.f}, lhs[2] = {0.f, 0.f};
  float sY2[2] = {0.f, 0.f}, sYH[2] = {0.f, 0.f};

  for (int c4 = 0; c4 < 4; ++c4) {
    __syncthreads();   // previous chunk's reads done
    for (int e = tid; e < 2048; e += 256) {
      int ch = e >> 8, c = e & 255;
      float2 val = bufA[((size_t)(c4 * 8 + ch) << 17) + (size_t)v * 256 + c];
      s[ch][PHY(brev9((c + 384) & 511))] = val;
      s[ch][PHY(brev9(c + 128))] = make_float2(0.f, 0.f);
    }
    __syncthreads();
    fft512_r4_fwd_rows(s, tid);
    #pragma unroll
    for (int uu = 0; uu < 2; ++uu) {
      float kk = kkA[uu];
      float2 w0 = zw[uu], w1 = zwpi[uu];
      #pragma unroll
      for (int ch = 0; ch < 8; ++ch) {
        float dl = dly[c4 * 8 + ch];
        float sd, cd2;
        __sincosf(kk * dl, &sd, &cd2);
        // H = 0.5*(conj(zd)*zw + zd*conj(zwpi)), zd = exp(i kk d)
        float t0r = cd2 * w0.x + sd * w0.y;
        float t0i = cd2 * w0.y - sd * w0.x;
        float t1r = cd2 * w1.x + sd * w1.y;
        float t1i = sd * w1.x - cd2 * w1.y;
        float Hr = 0.5f * (t0r + t1r);
        float Hi = 0.5f * (t0i + t1i);
        float2 Yv = s[ch][up[uu]];
        rhsr[uu] += Yv.x * Hr + Yv.y * Hi;
        rhsi[uu] += Yv.y * Hr - Yv.x * Hi;
        float h2 = Hr * Hr + Hi * Hi;
        float y2 = Yv.x * Yv.x + Yv.y * Yv.y;
        lhs[uu] += h2;
        sY2[uu] += y2;
        sYH[uu] += sqrtf(y2 * h2);
      }
    }
  }
  // finalize X (registers) + weighted loss (Hermitian doubling)
  float lw = (v == 0 || v == 256) ? 1.f : 2.f;
  float2 Xv[2];
  float lsum = 0.f;
  #pragma unroll
  for (int uu = 0; uu < 2; ++uu) {
    float Xr = rhsr[uu] / lhs[uu], Xi = rhsi[uu] / lhs[uu];
    Xv[uu] = make_float2(Xr, Xi);
    float aX = sqrtf(Xr * Xr + Xi * Xi);
    float kk2 = kkA[uu] * kkA[uu];
    lsum += kk2 * (sY2[uu] - 2.f * aX * sYH[uu] + aX * aX * lhs[uu]);
  }
  float bs = block_reduce_any(lsum * lw);
  if (threadIdx.x == 0) atomicAdd(&acc[0], bs);
  // fused u-axis inverse FFT of this v's X row (reuse LDS row 0)
  __syncthreads();
  float2* s0 = &s[0][0];
  s0[PHY(brev9(tid))] = Xv[0];
  s0[PHY(brev9(tid + 256))] = Xv[1];
  __syncthreads();
  fft512_r4_row(s0, tid, +1.f);
  const float sc = 1.f / 512.f;
  float2 o0 = s0[PHY(tid)], o1 = s0[PHY(tid + 256)];
  o0.x *= sc; o0.y *= sc; o1.x *= sc; o1.y *= sc;
  Xo[((size_t)v << 9) + tid] = o0;
  Xo[((size_t)v << 9) + tid + 256] = o1;
  if (v != 0 && v != 256) {
    int vm = 512 - v;
    Xo[((size_t)vm << 9) + tid] = make_float2(o0.x, -o0.y);
    Xo[((size_t)vm << 9) + tid + 256] = make_float2(o1.x, -o1.y);
  }
}

// ---------------- K5: in-place paired-tile transpose ----------------
__global__ __launch_bounds__(256) void k_transpose_ip(float2* __restrict__ B) {
  int ti = blockIdx.x, tj = blockIdx.y;
  if (ti > tj) return;
  __shared__ float2 At[32][33];
  __shared__ float2 Bt[32][33];
  int tid = threadIdx.x;
  for (int e = tid; e < 1024; e += 256) {
    int r = e >> 5, c = e & 31;
    At[r][c] = B[(size_t)(ti * 32 + r) * 512 + tj * 32 + c];
    if (ti != tj) Bt[r][c] = B[(size_t)(tj * 32 + r) * 512 + ti * 32 + c];
  }
  __syncthreads();
  for (int e = tid; e < 1024; e += 256) {
    int r = e >> 5, c = e & 31;
    B[(size_t)(tj * 32 + r) * 512 + ti * 32 + c] = At[c][r];
    if (ti != tj) B[(size_t)(ti * 32 + r) * 512 + tj * 32 + c] = Bt[c][r];
  }
}

// ---------------- K6: final inverse row FFT (radix-4) + fftshift store -----
__global__ __launch_bounds__(256) void k_final_rows(const float2* __restrict__ buf,
                                                    float* __restrict__ xrec) {
  __shared__ float2 s[RSW];
  int arow = blockIdx.x;
  const float2* p = buf + ((size_t)arow << 9);
  int tid = threadIdx.x;
  s[PHY(brev9(tid))] = p[tid];
  s[PHY(brev9(tid + 256))] = p[tid + 256];
  __syncthreads();
  fft512_r4_row(s, tid, +1.f);
  int orow = (arow + 256) & 511;
  const float sc = 1.f / 512.f;
  xrec[(orow << 9) + ((tid + 256) & 511)] = s[PHY(tid)].x * sc;
  xrec[(orow << 9) + (tid & 511)] = s[PHY(tid + 256)].x * sc;
}

// ---------------- K7: TV + L1 reductions (atomics only, NO fence) ----------
__global__ __launch_bounds__(256) void k_tvl1(const float* __restrict__ sos,
                                              const float* __restrict__ mask,
                                              float* __restrict__ acc) {
  int t = blockIdx.x * 256 + threadIdx.x;
  float s = sos[t];
  float m = mask[t];
  int i = t >> 9, j = t & 511;
  float tv = 0.f;
  if (i > 0) tv += fabsf((s - sos[t - 512]) * m);
  if (j > 0) tv += fabsf((s - sos[t - 1]) * m);
  float l1 = fabsf(s - 1550.f) * m;
  float tvb = block_reduce_any(tv);
  float l1b = block_reduce_any(l1);
  if (threadIdx.x == 0) {
    atomicAdd(&acc[1], tvb);
    atomicAdd(&acc[2], l1b);
  }
}

// ---------------- K8: finalize loss (separate launch = ordering) ----------
__global__ void k_finalize(const float* __restrict__ acc, float* __restrict__ out) {
  out[0] = acc[0] * (1.f / 8388608.f) + 1e-3f * acc[1] + 1e-3f * (acc[2] * (1.f / 262144.f));
}

// ---------------- launch ----------------
extern "C" void kernel_launch(void* const* d_in, const int* in_sizes, int n_in,
                              void* d_out, int out_size, void* d_ws, size_t ws_size,
                              hipStream_t stream) {
  const float* W1 = (const float*)d_in[0];
  const float* b1 = (const float*)d_in[1];
  const float* W2 = (const float*)d_in[2];
  const float* b2 = (const float*)d_in[3];
  const float* W3 = (const float*)d_in[4];
  const float* b3 = (const float*)d_in[5];
  const float* W4 = (const float*)d_in[6];
  const float* b4 = (const float*)d_in[7];
  const float* y_img = (const float*)d_in[8];
  const float* delays = (const float*)d_in[9];
  const float* xq = (const float*)d_in[10];
  const float* yq = (const float*)d_in[11];
  const float* mgrid = (const float*)d_in[12];
  const float* mask = (const float*)d_in[13];
  const int* mask_idx = (const int*)d_in[14];
  const float* x_vec = (const float*)d_in[15];
  const float* y_vec = (const float*)d_in[16];
  const int M = in_sizes[14];
  const int nMlp = (M + MLP_P - 1) / MLP_P;

  float* out = (float*)d_out;
  float* xrec = out;                    // 262144
  float* sos = out + SOS_ELEMS;         // 262144
  float* loss = out + 2 * SOS_ELEMS;    // 1

  char* wsb = (char*)d_ws;
  float* acc = (float*)wsb;                                     // 4 floats
  float* wfs = (float*)(wsb + 1024);                            // 240 floats
  float2* bufA = (float2*)(wsb + 4096);                         // 32ch x 131072 c64
  float2* bufX = (float2*)(wsb + 4096 + (size_t)NDEL * 512 * 256 * sizeof(float2)); // 2 MB

  k_init<<<1024, 256, 0, stream>>>(sos, acc);
  k_mlp<<<nMlp, 128, 0, stream>>>(W1, b1, W2, b2, W3, b3, W4, b4,
                                  mgrid, mask_idx, M, sos);
  k_wavefront<<<NTH, 256, 0, stream>>>(sos, xq, yq, x_vec, y_vec, wfs);
  k_fwdT<<<dim3(32, NDEL), 256, 0, stream>>>(y_img, bufA);
  k_colfft_deconv<<<257, 256, 0, stream>>>(bufA, delays, wfs, bufX, acc); // Hermitian half
  k_transpose_ip<<<dim3(16, 16), 256, 0, stream>>>(bufX);
  k_final_rows<<<512, 256, 0, stream>>>(bufX, xrec);
  k_tvl1<<<1024, 256, 0, stream>>>(sos, mask, acc);
  k_finalize<<<1, 1, 0, stream>>>(acc, loss);
}

// Round 17
// 219.534 us; speedup vs baseline: 1.1727x; 1.0155x over previous
//
#include <hip/hip_runtime.h>
#include <hip/hip_bf16.h>
#include <math.h>

// ---------------- constants ----------------
#define NP 512
#define NIMG 256
#define NDEL 32
#define NTH 240
#define NINT 250
#define SOS_ELEMS (512*512)
#define MLP_P 32
// swizzled physical index for FFT LDS rows
#define PHY(i) ((i) + ((i) >> 3))
#define RSW 576   // PHY(511)=574 -> row array size
#define PI_F 3.14159265358979323846f

__device__ __forceinline__ int brev9(int i) { return (int)(__brev((unsigned)i) >> 23); }

__device__ __forceinline__ float block_reduce_any(float v) {
  #pragma unroll
  for (int o = 32; o > 0; o >>= 1) v += __shfl_down(v, o, 64);
  __shared__ float red[8];
  int lane = threadIdx.x & 63, wid = threadIdx.x >> 6;
  __syncthreads();
  if (lane == 0) red[wid] = v;
  __syncthreads();
  float r = 0.f;
  if (threadIdx.x == 0) {
    int nw = blockDim.x >> 6;
    for (int i = 0; i < nw; ++i) r += red[i];
  }
  return r;
}

// ---- radix-4 FFT core butterfly (sign = -1 fwd, +1 inv) ----
__device__ __forceinline__ void r4_bfly(float2& x0, float2& x1, float2& x2, float2& x3,
                                        float c1, float s1n, float c2, float s2n, float sign) {
  float t1x = x1.x * c1 - x1.y * s1n, t1y = x1.x * s1n + x1.y * c1;
  float y0x = x0.x + t1x, y0y = x0.y + t1y;
  float y1x = x0.x - t1x, y1y = x0.y - t1y;
  float t3x = x3.x * c1 - x3.y * s1n, t3y = x3.x * s1n + x3.y * c1;
  float y2x = x2.x + t3x, y2y = x2.y + t3y;
  float y3x = x2.x - t3x, y3y = x2.y - t3y;
  float t2x = y2x * c2 - y2y * s2n, t2y = y2x * s2n + y2y * c2;
  float ux = y3x * c2 - y3y * s2n, uy = y3x * s2n + y3y * c2;
  float t4x = -sign * uy, t4y = sign * ux;   // rotate by sign*i (fwd: -i)
  x0 = make_float2(y0x + t2x, y0y + t2y);
  x2 = make_float2(y0x - t2x, y0y - t2y);
  x1 = make_float2(y1x + t4x, y1y + t4y);
  x3 = make_float2(y1x - t4x, y1y - t4y);
}

// radix-4 FFT, 512 pts x 8 rows, 256 threads, swizzled LDS, forward.
__device__ __forceinline__ void fft512_r4_fwd_rows(float2 (*s)[RSW], int tid) {
  #pragma unroll
  for (int pass = 0; pass < 4; ++pass) {
    const int sh = 2 * pass;
    const int h = 1 << sh;
    int p = tid & 127;
    int rbase = (tid >> 7) << 2;
    int j = p & (h - 1);
    int g = p >> sh;
    int base = (g << (sh + 2)) + j;
    int i0 = PHY(base), i1 = PHY(base + h), i2 = PHY(base + 2 * h), i3 = PHY(base + 3 * h);
    float ang1 = -PI_F * (float)j / (float)h;
    float s1n, c1; __sincosf(ang1, &s1n, &c1);
    float s2n, c2; __sincosf(0.5f * ang1, &s2n, &c2);
    #pragma unroll
    for (int rr = 0; rr < 4; ++rr) {
      int r = rbase + rr;
      float2 x0 = s[r][i0], x1 = s[r][i1], x2 = s[r][i2], x3 = s[r][i3];
      r4_bfly(x0, x1, x2, x3, c1, s1n, c2, s2n, -1.f);
      s[r][i0] = x0; s[r][i1] = x1; s[r][i2] = x2; s[r][i3] = x3;
    }
    __syncthreads();
  }
  {
    int p = tid;
    int i1 = PHY(p), i2 = PHY(p + 256);
    float ang = -PI_F * (float)p * (1.f / 256.f);
    float sn, cs; __sincosf(ang, &sn, &cs);
    #pragma unroll
    for (int r = 0; r < 8; ++r) {
      float2 a = s[r][i1], b = s[r][i2];
      float tr = b.x * cs - b.y * sn;
      float ti = b.x * sn + b.y * cs;
      s[r][i1] = make_float2(a.x + tr, a.y + ti);
      s[r][i2] = make_float2(a.x - tr, a.y - ti);
    }
    __syncthreads();
  }
}

// radix-4 FFT, 512 pts x 4 rows (packed real pairs), 256 threads.
__device__ __forceinline__ void fft512_r4_fwd_rows4(float2 (*s)[RSW], int tid) {
  #pragma unroll
  for (int pass = 0; pass < 4; ++pass) {
    const int sh = 2 * pass;
    const int h = 1 << sh;
    int p = tid & 127;
    int rbase = (tid >> 7) << 1;
    int j = p & (h - 1);
    int g = p >> sh;
    int base = (g << (sh + 2)) + j;
    int i0 = PHY(base), i1 = PHY(base + h), i2 = PHY(base + 2 * h), i3 = PHY(base + 3 * h);
    float ang1 = -PI_F * (float)j / (float)h;
    float s1n, c1; __sincosf(ang1, &s1n, &c1);
    float s2n, c2; __sincosf(0.5f * ang1, &s2n, &c2);
    #pragma unroll
    for (int rr = 0; rr < 2; ++rr) {
      int r = rbase + rr;
      float2 x0 = s[r][i0], x1 = s[r][i1], x2 = s[r][i2], x3 = s[r][i3];
      r4_bfly(x0, x1, x2, x3, c1, s1n, c2, s2n, -1.f);
      s[r][i0] = x0; s[r][i1] = x1; s[r][i2] = x2; s[r][i3] = x3;
    }
    __syncthreads();
  }
  {
    int p = tid;
    int i1 = PHY(p), i2 = PHY(p + 256);
    float ang = -PI_F * (float)p * (1.f / 256.f);
    float sn, cs; __sincosf(ang, &sn, &cs);
    #pragma unroll
    for (int r = 0; r < 4; ++r) {
      float2 a = s[r][i1], b = s[r][i2];
      float tr = b.x * cs - b.y * sn;
      float ti = b.x * sn + b.y * cs;
      s[r][i1] = make_float2(a.x + tr, a.y + ti);
      s[r][i2] = make_float2(a.x - tr, a.y - ti);
    }
    __syncthreads();
  }
}

// radix-4 FFT, single 512-pt row, 256 threads, swizzled LDS, sign-param.
__device__ __forceinline__ void fft512_r4_row(float2* s, int tid, float sign) {
  #pragma unroll
  for (int pass = 0; pass < 4; ++pass) {
    const int sh = 2 * pass;
    const int h = 1 << sh;
    if (tid < 128) {
      int j = tid & (h - 1);
      int g = tid >> sh;
      int base = (g << (sh + 2)) + j;
      int i0 = PHY(base), i1 = PHY(base + h), i2 = PHY(base + 2 * h), i3 = PHY(base + 3 * h);
      float ang1 = sign * PI_F * (float)j / (float)h;
      float s1n, c1; __sincosf(ang1, &s1n, &c1);
      float s2n, c2; __sincosf(0.5f * ang1, &s2n, &c2);
      float2 x0 = s[i0], x1 = s[i1], x2 = s[i2], x3 = s[i3];
      r4_bfly(x0, x1, x2, x3, c1, s1n, c2, s2n, sign);
      s[i0] = x0; s[i1] = x1; s[i2] = x2; s[i3] = x3;
    }
    __syncthreads();
  }
  {
    int i1 = PHY(tid), i2 = PHY(tid + 256);
    float ang = sign * PI_F * (float)tid * (1.f / 256.f);
    float sn, cs; __sincosf(ang, &sn, &cs);
    float2 a = s[i1], b = s[i2];
    float tr = b.x * cs - b.y * sn;
    float ti = b.x * sn + b.y * cs;
    s[i1] = make_float2(a.x + tr, a.y + ti);
    s[i2] = make_float2(a.x - tr, a.y - ti);
    __syncthreads();
  }
}

// ---------------- K1: SIREN MLP + scatter + SoS background + acc zero ------
// 32 pts/block, 128 threads = 8 pg(4 pts) x 16 jg(8 j split {4jg, 64+4jg}).
// DO NOT retile: R10 split / R11 shrink / R15 16-row wbuf all regressed.
// Also fills sos background (mask==0 pixels) and zeroes acc (replaces k_init).
__global__ __launch_bounds__(128) void k_mlp(
    const float* __restrict__ W1, const float* __restrict__ b1,
    const float* __restrict__ W2, const float* __restrict__ b2,
    const float* __restrict__ W3, const float* __restrict__ b3,
    const float* __restrict__ W4v, const float* __restrict__ b4,
    const float* __restrict__ mgrid, const int* __restrict__ mask_idx,
    const float* __restrict__ mask, int M,
    float* __restrict__ sos, float* __restrict__ acc) {
  __shared__ float hbuf[MLP_P][132];
  __shared__ float wbuf[2][8][132];
  __shared__ float xy2[MLP_P][2];
  int tid = threadIdx.x;
  int base = blockIdx.x * MLP_P;
  if (tid < MLP_P * 2) {
    int p = tid >> 1, c = tid & 1;
    float v = 0.f;
    if (base + p < M) v = mgrid[(base + p) * 2 + c];
    xy2[p][c] = v;
  }
  // acc zero (block 0)
  if (blockIdx.x == 0 && tid < 4) acc[tid] = 0.f;
  // SoS background: each block covers 256-pixel slabs; write where mask==0
  for (int slab = blockIdx.x; slab < 1024; slab += gridDim.x) {
    #pragma unroll
    for (int e = 0; e < 2; ++e) {
      int t = slab * 256 + tid + e * 128;
      if (mask[t] == 0.f) sos[t] = 1499.363f;
    }
  }
  __syncthreads();
  for (int e = tid; e < MLP_P * 128; e += 128) {
    int p = e >> 7, j = e & 127;
    hbuf[p][j] = __sinf(30.f * (xy2[p][0] * W1[j] + xy2[p][1] * W1[128 + j] + b1[j]));
  }
  __syncthreads();

  int jg = tid & 15, pg = tid >> 4;
  int jA = jg * 4, jB = 64 + jg * 4;
  int p0 = pg * 4;
  int wr = tid >> 4, wc = (tid & 15) << 3;
  #pragma unroll
  for (int layer = 0; layer < 2; ++layer) {
    const float* Wg = layer ? W3 : W2;
    const float* bb = layer ? b3 : b2;
    float acr[4][8];
    #pragma unroll
    for (int i = 0; i < 4; ++i)
      #pragma unroll
      for (int j = 0; j < 8; ++j) acr[i][j] = 0.f;

    float4 pre1 = *(const float4*)&Wg[wr * 128 + wc];
    float4 pre2 = *(const float4*)&Wg[wr * 128 + wc + 4];
    for (int c = 0; c < 16; ++c) {
      *(float4*)&wbuf[c & 1][wr][wc] = pre1;
      *(float4*)&wbuf[c & 1][wr][wc + 4] = pre2;
      __syncthreads();
      if (c < 15) {
        pre1 = *(const float4*)&Wg[((c + 1) * 8 + wr) * 128 + wc];
        pre2 = *(const float4*)&Wg[((c + 1) * 8 + wr) * 128 + wc + 4];
      }
      int k0 = c * 8;
      float hreg[4][8];
      #pragma unroll
      for (int i = 0; i < 4; ++i) {
        float4 ha = *(const float4*)&hbuf[p0 + i][k0];
        float4 hb = *(const float4*)&hbuf[p0 + i][k0 + 4];
        hreg[i][0] = ha.x; hreg[i][1] = ha.y; hreg[i][2] = ha.z; hreg[i][3] = ha.w;
        hreg[i][4] = hb.x; hreg[i][5] = hb.y; hreg[i][6] = hb.z; hreg[i][7] = hb.w;
      }
      #pragma unroll
      for (int kk = 0; kk < 8; ++kk) {
        float4 wa = *(const float4*)&wbuf[c & 1][kk][jA];
        float4 wb = *(const float4*)&wbuf[c & 1][kk][jB];
        float w8[8] = {wa.x, wa.y, wa.z, wa.w, wb.x, wb.y, wb.z, wb.w};
        #pragma unroll
        for (int i = 0; i < 4; ++i) {
          float hv = hreg[i][kk];
          #pragma unroll
          for (int j = 0; j < 8; ++j) acr[i][j] += hv * w8[j];
        }
      }
    }
    float breg[8];
    #pragma unroll
    for (int j = 0; j < 4; ++j) { breg[j] = bb[jA + j]; breg[4 + j] = bb[jB + j]; }
    __syncthreads();
    #pragma unroll
    for (int i = 0; i < 4; ++i) {
      float o[8];
      #pragma unroll
      for (int j = 0; j < 8; ++j) o[j] = __sinf(30.f * (acr[i][j] + breg[j]));
      *(float4*)&hbuf[p0 + i][jA] = make_float4(o[0], o[1], o[2], o[3]);
      *(float4*)&hbuf[p0 + i][jB] = make_float4(o[4], o[5], o[6], o[7]);
    }
    __syncthreads();
  }
  {
    int p = tid >> 2, q = tid & 3;
    float s = 0.f;
    #pragma unroll
    for (int k = 0; k < 32; k += 4) {
      float4 h4 = *(const float4*)&hbuf[p][q * 32 + k];
      float4 w4 = *(const float4*)&W4v[q * 32 + k];
      s += h4.x * w4.x + h4.y * w4.y + h4.z * w4.z + h4.w * w4.w;
    }
    s += __shfl_down(s, 1, 64);
    s += __shfl_down(s, 2, 64);
    if (q == 0 && base + p < M)
      sos[mask_idx[base + p]] = (s + b4[0]) * 170.f + 1550.f;
  }
}

// ---------------- K2: wavefront ray integrals ----------------
__global__ __launch_bounds__(256) void k_wavefront(
    const float* __restrict__ sos, const float* __restrict__ xq_p,
    const float* __restrict__ yq_p, const float* __restrict__ x_vec,
    const float* __restrict__ y_vec, float* __restrict__ wfs) {
  int i = blockIdx.x;
  int j = threadIdx.x;
  float xq = xq_p[0], yq = yq_p[0];
  float r = sqrtf(xq * xq + yq * yq);
  float phi = atan2f(xq, yq);
  float th = (float)((double)i * (2.0 * M_PI / 239.0));
  float s = sinf(th - phi), cd = cosf(th - phi);
  const float R2 = 0.008f * 0.008f;
  float disc = fmaxf(R2 - (r * s) * (r * s), 0.f);
  float sq = sqrtf(disc);
  float l_in = sq + r * cd;
  float l_out = 2.f * sq * (cd >= 0.f ? 1.f : 0.f);
  float l = (r < 0.008f) ? l_in : l_out;
  float x0 = x_vec[0], dx = x_vec[1] - x_vec[0];
  float y0 = y_vec[0], dy = y_vec[1] - y_vec[0];
  float sinth = sinf(th), costh = cosf(th);
  float contrib = 0.f;
  if (j < NINT) {
    float sj = (float)j * (1.f / 249.f);
    int xi = (int)rintf((xq - l * sj * sinth - x0) / dx);
    int yi = (int)rintf((yq - l * sj * costh - y0) / dy);
    float sv = sos[(((-yi) & 511) << 9) + (xi & 511)];
    float f = 1.f - 1500.f / sv;
    float wgt = (j == 0 || j == NINT - 1) ? 0.5f : 1.f;
    contrib = wgt * f;
  }
  float tot = block_reduce_any(contrib);
  if (threadIdx.x == 0) wfs[i] = tot * l * (1.f / 249.f);
}

// ---------------- K3: windowed v-axis FFT, REAL-PAIR packed (4 FFTs/block) -
// z = row_a + i*row_b; Y_a=(Z(v)+conj(Z(-v)))/2, Y_b=-i(Z(v)-conj(Z(-v)))/2.
// Hermitian: only v=0..256 rows stored.
__global__ __launch_bounds__(256) void k_fwdT(const float* __restrict__ y_img,
                                              float2* __restrict__ bufA) {
  __shared__ float2 s[4][RSW];
  int rt = blockIdx.x;
  int d = blockIdx.y;
  int tid = threadIdx.x;
  const float INV2S2 = (float)(0.6931471805599453 / 1406.25);
  for (int e = tid; e < 2048; e += 256) {
    int i = e >> 8, c = e & 255;
    int r = rt * 8 + i;
    float axr = (float)r - 127.5f;
    float axc = (float)c - 127.5f;
    float g = __expf(-(axr * axr + axc * axc) * INV2S2);
    float val = y_img[((size_t)d << 16) + (r << 8) + c] * g;
    int p = i >> 1, comp = i & 1;
    ((float*)&s[p][PHY(brev9((c + 384) & 511))])[comp] = val;
    ((float*)&s[p][PHY(brev9(c + 128))])[comp] = 0.f;
  }
  __syncthreads();
  fft512_r4_fwd_rows4(s, tid);
  float2* outp = bufA + ((size_t)d << 17) + rt * 8;
  for (int e = tid; e < 2056; e += 256) {   // 257 v-rows x 8
    int i = e & 7, v = e >> 3;
    int p = i >> 1, comp = i & 1;
    float2 Zv = s[p][PHY(v)];
    float2 Zm = s[p][PHY((512 - v) & 511)];
    float2 Yv;
    if (comp == 0) Yv = make_float2(0.5f * (Zv.x + Zm.x), 0.5f * (Zv.y - Zm.y));
    else           Yv = make_float2(0.5f * (Zv.y + Zm.y), 0.5f * (Zm.x - Zv.x));
    outp[(size_t)v * 256 + i] = Yv;
  }
}

// ---------------- K4: TV + L1 reductions (atomics only, NO fence) ----------
__global__ __launch_bounds__(256) void k_tvl1(const float* __restrict__ sos,
                                              const float* __restrict__ mask,
                                              float* __restrict__ acc) {
  int t = blockIdx.x * 256 + threadIdx.x;
  float s = sos[t];
  float m = mask[t];
  int i = t >> 9, j = t & 511;
  float tv = 0.f;
  if (i > 0) tv += fabsf((s - sos[t - 512]) * m);
  if (j > 0) tv += fabsf((s - sos[t - 1]) * m);
  float l1 = fabsf(s - 1550.f) * m;
  float tvb = block_reduce_any(tv);
  float l1b = block_reduce_any(l1);
  if (threadIdx.x == 0) {
    atomicAdd(&acc[1], tvb);
    atomicAdd(&acc[2], l1b);
  }
}

// ---------------- K5: u-axis FFT + deconv + loss + u-axis ifft of X --------
// Hermitian-halved: grid = 257 v-blocks; loss weight 2 for v in [1,255];
// mirror store X(512-v) = conj(X(v)) after the u-ifft.
__device__ __forceinline__ float interp_wf(const float* wfs, float xn) {
  const float dxg = (float)(2.0 * M_PI / 239.0);
  float t = xn / dxg;
  int f = (int)floorf(t); f = min(max(f, 0), 239);
  int c = (int)ceilf(t);  c = min(max(c, 0), 239);
  float yf = wfs[f], yc = wfs[c];
  if (c == f) return yc;
  float xgf = (float)f * dxg;
  return yf + (yc - yf) * (xn - xgf) / ((float)(c - f) * dxg);
}

__global__ __launch_bounds__(256) void k_colfft_deconv(
    const float2* __restrict__ bufA, const float* __restrict__ delays,
    const float* __restrict__ wfs_g, float2* __restrict__ Xo,
    float* __restrict__ acc) {
  __shared__ float2 s[8][RSW];
  __shared__ float wfs[NTH];
  __shared__ float dly[NDEL];
  int v = blockIdx.x;            // 0..256
  int tid = threadIdx.x;
  if (tid < NTH) wfs[tid] = wfs_g[tid];
  if (tid < NDEL) dly[tid] = delays[tid];
  __syncthreads();

  const float inv_nd = 1.f / 0.02048f;
  const float TWO_PI = 6.28318530717958647692f;
  float fy = (float)(v < 256 ? v : v - 512) * inv_nd;
  float kkA[2];
  float2 zw[2], zwpi[2];   // exp(i kk w), exp(i kk wpi)
  int up[2];
  #pragma unroll
  for (int uu = 0; uu < 2; ++uu) {
    int u = tid + 256 * uu;
    up[uu] = PHY(u);
    float fx = (float)(u < 256 ? u : u - 512) * inv_nd;
    float kk = TWO_PI * sqrtf(fx * fx + fy * fy);
    kkA[uu] = kk;
    float th = atan2f(fy, fx);
    if (th < 0.f) th += TWO_PI;
    float w = interp_wf(wfs, th);
    float thpi = th + PI_F;
    if (thpi >= TWO_PI) thpi -= TWO_PI;
    float wpi = interp_wf(wfs, thpi);
    float snw, csw; __sincosf(kk * w, &snw, &csw);
    zw[uu] = make_float2(csw, snw);
    float snp, csp; __sincosf(kk * wpi, &snp, &csp);
    zwpi[uu] = make_float2(csp, snp);
  }

  float rhsr[2] = {0.f, 0.f}, rhsi[2] = {0.f, 0.f}, lhs[2] = {0.f, 0.f};
  float sY2[2] = {0.f, 0.f}, sYH[2] = {0.f, 0.f};

  for (int c4 = 0; c4 < 4; ++c4) {
    __syncthreads();   // previous chunk's reads done
    for (int e = tid; e < 2048; e += 256) {
      int ch = e >> 8, c = e & 255;
      float2 val = bufA[((size_t)(c4 * 8 + ch) << 17) + (size_t)v * 256 + c];
      s[ch][PHY(brev9((c + 384) & 511))] = val;
      s[ch][PHY(brev9(c + 128))] = make_float2(0.f, 0.f);
    }
    __syncthreads();
    fft512_r4_fwd_rows(s, tid);
    #pragma unroll
    for (int uu = 0; uu < 2; ++uu) {
      float kk = kkA[uu];
      float2 w0 = zw[uu], w1 = zwpi[uu];
      #pragma unroll
      for (int ch = 0; ch < 8; ++ch) {
        float dl = dly[c4 * 8 + ch];
        float sd, cd2;
        __sincosf(kk * dl, &sd, &cd2);
        // H = 0.5*(conj(zd)*zw + zd*conj(zwpi)), zd = exp(i kk d)
        float t0r = cd2 * w0.x + sd * w0.y;
        float t0i = cd2 * w0.y - sd * w0.x;
        float t1r = cd2 * w1.x + sd * w1.y;
        float t1i = sd * w1.x - cd2 * w1.y;
        float Hr = 0.5f * (t0r + t1r);
        float Hi = 0.5f * (t0i + t1i);
        float2 Yv = s[ch][up[uu]];
        rhsr[uu] += Yv.x * Hr + Yv.y * Hi;
        rhsi[uu] += Yv.y * Hr - Yv.x * Hi;
        float h2 = Hr * Hr + Hi * Hi;
        float y2 = Yv.x * Yv.x + Yv.y * Yv.y;
        lhs[uu] += h2;
        sY2[uu] += y2;
        sYH[uu] += sqrtf(y2 * h2);
      }
    }
  }
  // finalize X (registers) + weighted loss (Hermitian doubling)
  float lw = (v == 0 || v == 256) ? 1.f : 2.f;
  float2 Xv[2];
  float lsum = 0.f;
  #pragma unroll
  for (int uu = 0; uu < 2; ++uu) {
    float Xr = rhsr[uu] / lhs[uu], Xi = rhsi[uu] / lhs[uu];
    Xv[uu] = make_float2(Xr, Xi);
    float aX = sqrtf(Xr * Xr + Xi * Xi);
    float kk2 = kkA[uu] * kkA[uu];
    lsum += kk2 * (sY2[uu] - 2.f * aX * sYH[uu] + aX * aX * lhs[uu]);
  }
  float bs = block_reduce_any(lsum * lw);
  if (threadIdx.x == 0) atomicAdd(&acc[0], bs);
  // fused u-axis inverse FFT of this v's X row (reuse LDS row 0)
  __syncthreads();
  float2* s0 = &s[0][0];
  s0[PHY(brev9(tid))] = Xv[0];
  s0[PHY(brev9(tid + 256))] = Xv[1];
  __syncthreads();
  fft512_r4_row(s0, tid, +1.f);
  const float sc = 1.f / 512.f;
  float2 o0 = s0[PHY(tid)], o1 = s0[PHY(tid + 256)];
  o0.x *= sc; o0.y *= sc; o1.x *= sc; o1.y *= sc;
  Xo[((size_t)v << 9) + tid] = o0;
  Xo[((size_t)v << 9) + tid + 256] = o1;
  if (v != 0 && v != 256) {
    int vm = 512 - v;
    Xo[((size_t)vm << 9) + tid] = make_float2(o0.x, -o0.y);
    Xo[((size_t)vm << 9) + tid + 256] = make_float2(o1.x, -o1.y);
  }
}

// ---------------- K6: in-place paired-tile transpose ----------------
__global__ __launch_bounds__(256) void k_transpose_ip(float2* __restrict__ B) {
  int ti = blockIdx.x, tj = blockIdx.y;
  if (ti > tj) return;
  __shared__ float2 At[32][33];
  __shared__ float2 Bt[32][33];
  int tid = threadIdx.x;
  for (int e = tid; e < 1024; e += 256) {
    int r = e >> 5, c = e & 31;
    At[r][c] = B[(size_t)(ti * 32 + r) * 512 + tj * 32 + c];
    if (ti != tj) Bt[r][c] = B[(size_t)(tj * 32 + r) * 512 + ti * 32 + c];
  }
  __syncthreads();
  for (int e = tid; e < 1024; e += 256) {
    int r = e >> 5, c = e & 31;
    B[(size_t)(tj * 32 + r) * 512 + ti * 32 + c] = At[c][r];
    if (ti != tj) B[(size_t)(ti * 32 + r) * 512 + tj * 32 + c] = Bt[c][r];
  }
}

// ---------------- K7: final inverse row FFT (radix-4) + fftshift store -----
// Also finalizes loss (block 0, thread 0) — colfft and tvl1 already done.
__global__ __launch_bounds__(256) void k_final_rows(const float2* __restrict__ buf,
                                                    float* __restrict__ xrec,
                                                    const float* __restrict__ acc,
                                                    float* __restrict__ lossout) {
  __shared__ float2 s[RSW];
  int arow = blockIdx.x;
  const float2* p = buf + ((size_t)arow << 9);
  int tid = threadIdx.x;
  if (arow == 0 && tid == 0)
    lossout[0] = acc[0] * (1.f / 8388608.f) + 1e-3f * acc[1] + 1e-3f * (acc[2] * (1.f / 262144.f));
  s[PHY(brev9(tid))] = p[tid];
  s[PHY(brev9(tid + 256))] = p[tid + 256];
  __syncthreads();
  fft512_r4_row(s, tid, +1.f);
  int orow = (arow + 256) & 511;
  const float sc = 1.f / 512.f;
  xrec[(orow << 9) + ((tid + 256) & 511)] = s[PHY(tid)].x * sc;
  xrec[(orow << 9) + (tid & 511)] = s[PHY(tid + 256)].x * sc;
}

// ---------------- launch ----------------
extern "C" void kernel_launch(void* const* d_in, const int* in_sizes, int n_in,
                              void* d_out, int out_size, void* d_ws, size_t ws_size,
                              hipStream_t stream) {
  const float* W1 = (const float*)d_in[0];
  const float* b1 = (const float*)d_in[1];
  const float* W2 = (const float*)d_in[2];
  const float* b2 = (const float*)d_in[3];
  const float* W3 = (const float*)d_in[4];
  const float* b3 = (const float*)d_in[5];
  const float* W4 = (const float*)d_in[6];
  const float* b4 = (const float*)d_in[7];
  const float* y_img = (const float*)d_in[8];
  const float* delays = (const float*)d_in[9];
  const float* xq = (const float*)d_in[10];
  const float* yq = (const float*)d_in[11];
  const float* mgrid = (const float*)d_in[12];
  const float* mask = (const float*)d_in[13];
  const int* mask_idx = (const int*)d_in[14];
  const float* x_vec = (const float*)d_in[15];
  const float* y_vec = (const float*)d_in[16];
  const int M = in_sizes[14];
  const int nMlp = (M + MLP_P - 1) / MLP_P;

  float* out = (float*)d_out;
  float* xrec = out;                    // 262144
  float* sos = out + SOS_ELEMS;         // 262144
  float* loss = out + 2 * SOS_ELEMS;    // 1

  char* wsb = (char*)d_ws;
  float* acc = (float*)wsb;                                     // 4 floats
  float* wfs = (float*)(wsb + 1024);                            // 240 floats
  float2* bufA = (float2*)(wsb + 4096);                         // 32ch x 131072 c64
  float2* bufX = (float2*)(wsb + 4096 + (size_t)NDEL * 512 * 256 * sizeof(float2)); // 2 MB

  k_mlp<<<nMlp, 128, 0, stream>>>(W1, b1, W2, b2, W3, b3, W4, b4,
                                  mgrid, mask_idx, mask, M, sos, acc);
  k_wavefront<<<NTH, 256, 0, stream>>>(sos, xq, yq, x_vec, y_vec, wfs);
  k_fwdT<<<dim3(32, NDEL), 256, 0, stream>>>(y_img, bufA);
  k_tvl1<<<1024, 256, 0, stream>>>(sos, mask, acc);
  k_colfft_deconv<<<257, 256, 0, stream>>>(bufA, delays, wfs, bufX, acc); // Hermitian half
  k_transpose_ip<<<dim3(16, 16), 256, 0, stream>>>(bufX);
  k_final_rows<<<512, 256, 0, stream>>>(bufX, xrec, acc, loss);
}

// Round 18
// 209.719 us; speedup vs baseline: 1.2276x; 1.0468x over previous
//
#include <hip/hip_runtime.h>
#include <hip/hip_bf16.h>
#include <math.h>

// ---------------- constants ----------------
#define NP 512
#define NIMG 256
#define NDEL 32
#define NTH 240
#define NINT 250
#define SOS_ELEMS (512*512)
#define MLP_P 32
// swizzled physical index for FFT LDS rows
#define PHY(i) ((i) + ((i) >> 3))
#define RSW 576   // PHY(511)=574 -> row array size
#define PI_F 3.14159265358979323846f

__device__ __forceinline__ int brev9(int i) { return (int)(__brev((unsigned)i) >> 23); }

__device__ __forceinline__ float block_reduce_any(float v) {
  #pragma unroll
  for (int o = 32; o > 0; o >>= 1) v += __shfl_down(v, o, 64);
  __shared__ float red[8];
  int lane = threadIdx.x & 63, wid = threadIdx.x >> 6;
  __syncthreads();
  if (lane == 0) red[wid] = v;
  __syncthreads();
  float r = 0.f;
  if (threadIdx.x == 0) {
    int nw = blockDim.x >> 6;
    for (int i = 0; i < nw; ++i) r += red[i];
  }
  return r;
}

// ---- radix-4 FFT core butterfly (sign = -1 fwd, +1 inv) ----
__device__ __forceinline__ void r4_bfly(float2& x0, float2& x1, float2& x2, float2& x3,
                                        float c1, float s1n, float c2, float s2n, float sign) {
  float t1x = x1.x * c1 - x1.y * s1n, t1y = x1.x * s1n + x1.y * c1;
  float y0x = x0.x + t1x, y0y = x0.y + t1y;
  float y1x = x0.x - t1x, y1y = x0.y - t1y;
  float t3x = x3.x * c1 - x3.y * s1n, t3y = x3.x * s1n + x3.y * c1;
  float y2x = x2.x + t3x, y2y = x2.y + t3y;
  float y3x = x2.x - t3x, y3y = x2.y - t3y;
  float t2x = y2x * c2 - y2y * s2n, t2y = y2x * s2n + y2y * c2;
  float ux = y3x * c2 - y3y * s2n, uy = y3x * s2n + y3y * c2;
  float t4x = -sign * uy, t4y = sign * ux;   // rotate by sign*i (fwd: -i)
  x0 = make_float2(y0x + t2x, y0y + t2y);
  x2 = make_float2(y0x - t2x, y0y - t2y);
  x1 = make_float2(y1x + t4x, y1y + t4y);
  x3 = make_float2(y1x - t4x, y1y - t4y);
}

// radix-4 FFT, 512 pts x 8 rows, 256 threads, swizzled LDS, forward.
__device__ __forceinline__ void fft512_r4_fwd_rows(float2 (*s)[RSW], int tid) {
  #pragma unroll
  for (int pass = 0; pass < 4; ++pass) {
    const int sh = 2 * pass;
    const int h = 1 << sh;
    int p = tid & 127;
    int rbase = (tid >> 7) << 2;
    int j = p & (h - 1);
    int g = p >> sh;
    int base = (g << (sh + 2)) + j;
    int i0 = PHY(base), i1 = PHY(base + h), i2 = PHY(base + 2 * h), i3 = PHY(base + 3 * h);
    float ang1 = -PI_F * (float)j / (float)h;
    float s1n, c1; __sincosf(ang1, &s1n, &c1);
    float s2n, c2; __sincosf(0.5f * ang1, &s2n, &c2);
    #pragma unroll
    for (int rr = 0; rr < 4; ++rr) {
      int r = rbase + rr;
      float2 x0 = s[r][i0], x1 = s[r][i1], x2 = s[r][i2], x3 = s[r][i3];
      r4_bfly(x0, x1, x2, x3, c1, s1n, c2, s2n, -1.f);
      s[r][i0] = x0; s[r][i1] = x1; s[r][i2] = x2; s[r][i3] = x3;
    }
    __syncthreads();
  }
  {
    int p = tid;
    int i1 = PHY(p), i2 = PHY(p + 256);
    float ang = -PI_F * (float)p * (1.f / 256.f);
    float sn, cs; __sincosf(ang, &sn, &cs);
    #pragma unroll
    for (int r = 0; r < 8; ++r) {
      float2 a = s[r][i1], b = s[r][i2];
      float tr = b.x * cs - b.y * sn;
      float ti = b.x * sn + b.y * cs;
      s[r][i1] = make_float2(a.x + tr, a.y + ti);
      s[r][i2] = make_float2(a.x - tr, a.y - ti);
    }
    __syncthreads();
  }
}

// radix-4 FFT, 512 pts x 4 rows (packed real pairs), 256 threads.
__device__ __forceinline__ void fft512_r4_fwd_rows4(float2 (*s)[RSW], int tid) {
  #pragma unroll
  for (int pass = 0; pass < 4; ++pass) {
    const int sh = 2 * pass;
    const int h = 1 << sh;
    int p = tid & 127;
    int rbase = (tid >> 7) << 1;
    int j = p & (h - 1);
    int g = p >> sh;
    int base = (g << (sh + 2)) + j;
    int i0 = PHY(base), i1 = PHY(base + h), i2 = PHY(base + 2 * h), i3 = PHY(base + 3 * h);
    float ang1 = -PI_F * (float)j / (float)h;
    float s1n, c1; __sincosf(ang1, &s1n, &c1);
    float s2n, c2; __sincosf(0.5f * ang1, &s2n, &c2);
    #pragma unroll
    for (int rr = 0; rr < 2; ++rr) {
      int r = rbase + rr;
      float2 x0 = s[r][i0], x1 = s[r][i1], x2 = s[r][i2], x3 = s[r][i3];
      r4_bfly(x0, x1, x2, x3, c1, s1n, c2, s2n, -1.f);
      s[r][i0] = x0; s[r][i1] = x1; s[r][i2] = x2; s[r][i3] = x3;
    }
    __syncthreads();
  }
  {
    int p = tid;
    int i1 = PHY(p), i2 = PHY(p + 256);
    float ang = -PI_F * (float)p * (1.f / 256.f);
    float sn, cs; __sincosf(ang, &sn, &cs);
    #pragma unroll
    for (int r = 0; r < 4; ++r) {
      float2 a = s[r][i1], b = s[r][i2];
      float tr = b.x * cs - b.y * sn;
      float ti = b.x * sn + b.y * cs;
      s[r][i1] = make_float2(a.x + tr, a.y + ti);
      s[r][i2] = make_float2(a.x - tr, a.y - ti);
    }
    __syncthreads();
  }
}

// radix-4 FFT, single 512-pt row, 256 threads, swizzled LDS, sign-param.
__device__ __forceinline__ void fft512_r4_row(float2* s, int tid, float sign) {
  #pragma unroll
  for (int pass = 0; pass < 4; ++pass) {
    const int sh = 2 * pass;
    const int h = 1 << sh;
    if (tid < 128) {
      int j = tid & (h - 1);
      int g = tid >> sh;
      int base = (g << (sh + 2)) + j;
      int i0 = PHY(base), i1 = PHY(base + h), i2 = PHY(base + 2 * h), i3 = PHY(base + 3 * h);
      float ang1 = sign * PI_F * (float)j / (float)h;
      float s1n, c1; __sincosf(ang1, &s1n, &c1);
      float s2n, c2; __sincosf(0.5f * ang1, &s2n, &c2);
      float2 x0 = s[i0], x1 = s[i1], x2 = s[i2], x3 = s[i3];
      r4_bfly(x0, x1, x2, x3, c1, s1n, c2, s2n, sign);
      s[i0] = x0; s[i1] = x1; s[i2] = x2; s[i3] = x3;
    }
    __syncthreads();
  }
  {
    int i1 = PHY(tid), i2 = PHY(tid + 256);
    float ang = sign * PI_F * (float)tid * (1.f / 256.f);
    float sn, cs; __sincosf(ang, &sn, &cs);
    float2 a = s[i1], b = s[i2];
    float tr = b.x * cs - b.y * sn;
    float ti = b.x * sn + b.y * cs;
    s[i1] = make_float2(a.x + tr, a.y + ti);
    s[i2] = make_float2(a.x - tr, a.y - ti);
    __syncthreads();
  }
}

// ---------------- K1: SIREN MLP + scatter + SoS background + acc zero ------
// 32 pts/block, 128 threads = 8 pg(4 pts) x 16 jg(8 j split {4jg, 64+4jg}).
// DO NOT retile: R10 split / R11 shrink / R15 16-row wbuf all regressed.
__global__ __launch_bounds__(128) void k_mlp(
    const float* __restrict__ W1, const float* __restrict__ b1,
    const float* __restrict__ W2, const float* __restrict__ b2,
    const float* __restrict__ W3, const float* __restrict__ b3,
    const float* __restrict__ W4v, const float* __restrict__ b4,
    const float* __restrict__ mgrid, const int* __restrict__ mask_idx,
    const float* __restrict__ mask, int M,
    float* __restrict__ sos, float* __restrict__ acc) {
  __shared__ float hbuf[MLP_P][132];
  __shared__ float wbuf[2][8][132];
  __shared__ float xy2[MLP_P][2];
  int tid = threadIdx.x;
  int base = blockIdx.x * MLP_P;
  if (tid < MLP_P * 2) {
    int p = tid >> 1, c = tid & 1;
    float v = 0.f;
    if (base + p < M) v = mgrid[(base + p) * 2 + c];
    xy2[p][c] = v;
  }
  if (blockIdx.x == 0 && tid < 4) acc[tid] = 0.f;
  for (int slab = blockIdx.x; slab < 1024; slab += gridDim.x) {
    #pragma unroll
    for (int e = 0; e < 2; ++e) {
      int t = slab * 256 + tid + e * 128;
      if (mask[t] == 0.f) sos[t] = 1499.363f;
    }
  }
  __syncthreads();
  for (int e = tid; e < MLP_P * 128; e += 128) {
    int p = e >> 7, j = e & 127;
    hbuf[p][j] = __sinf(30.f * (xy2[p][0] * W1[j] + xy2[p][1] * W1[128 + j] + b1[j]));
  }
  __syncthreads();

  int jg = tid & 15, pg = tid >> 4;
  int jA = jg * 4, jB = 64 + jg * 4;
  int p0 = pg * 4;
  int wr = tid >> 4, wc = (tid & 15) << 3;
  #pragma unroll
  for (int layer = 0; layer < 2; ++layer) {
    const float* Wg = layer ? W3 : W2;
    const float* bb = layer ? b3 : b2;
    float acr[4][8];
    #pragma unroll
    for (int i = 0; i < 4; ++i)
      #pragma unroll
      for (int j = 0; j < 8; ++j) acr[i][j] = 0.f;

    float4 pre1 = *(const float4*)&Wg[wr * 128 + wc];
    float4 pre2 = *(const float4*)&Wg[wr * 128 + wc + 4];
    for (int c = 0; c < 16; ++c) {
      *(float4*)&wbuf[c & 1][wr][wc] = pre1;
      *(float4*)&wbuf[c & 1][wr][wc + 4] = pre2;
      __syncthreads();
      if (c < 15) {
        pre1 = *(const float4*)&Wg[((c + 1) * 8 + wr) * 128 + wc];
        pre2 = *(const float4*)&Wg[((c + 1) * 8 + wr) * 128 + wc + 4];
      }
      int k0 = c * 8;
      float hreg[4][8];
      #pragma unroll
      for (int i = 0; i < 4; ++i) {
        float4 ha = *(const float4*)&hbuf[p0 + i][k0];
        float4 hb = *(const float4*)&hbuf[p0 + i][k0 + 4];
        hreg[i][0] = ha.x; hreg[i][1] = ha.y; hreg[i][2] = ha.z; hreg[i][3] = ha.w;
        hreg[i][4] = hb.x; hreg[i][5] = hb.y; hreg[i][6] = hb.z; hreg[i][7] = hb.w;
      }
      #pragma unroll
      for (int kk = 0; kk < 8; ++kk) {
        float4 wa = *(const float4*)&wbuf[c & 1][kk][jA];
        float4 wb = *(const float4*)&wbuf[c & 1][kk][jB];
        float w8[8] = {wa.x, wa.y, wa.z, wa.w, wb.x, wb.y, wb.z, wb.w};
        #pragma unroll
        for (int i = 0; i < 4; ++i) {
          float hv = hreg[i][kk];
          #pragma unroll
          for (int j = 0; j < 8; ++j) acr[i][j] += hv * w8[j];
        }
      }
    }
    float breg[8];
    #pragma unroll
    for (int j = 0; j < 4; ++j) { breg[j] = bb[jA + j]; breg[4 + j] = bb[jB + j]; }
    __syncthreads();
    #pragma unroll
    for (int i = 0; i < 4; ++i) {
      float o[8];
      #pragma unroll
      for (int j = 0; j < 8; ++j) o[j] = __sinf(30.f * (acr[i][j] + breg[j]));
      *(float4*)&hbuf[p0 + i][jA] = make_float4(o[0], o[1], o[2], o[3]);
      *(float4*)&hbuf[p0 + i][jB] = make_float4(o[4], o[5], o[6], o[7]);
    }
    __syncthreads();
  }
  {
    int p = tid >> 2, q = tid & 3;
    float s = 0.f;
    #pragma unroll
    for (int k = 0; k < 32; k += 4) {
      float4 h4 = *(const float4*)&hbuf[p][q * 32 + k];
      float4 w4 = *(const float4*)&W4v[q * 32 + k];
      s += h4.x * w4.x + h4.y * w4.y + h4.z * w4.z + h4.w * w4.w;
    }
    s += __shfl_down(s, 1, 64);
    s += __shfl_down(s, 2, 64);
    if (q == 0 && base + p < M)
      sos[mask_idx[base + p]] = (s + b4[0]) * 170.f + 1550.f;
  }
}

// ---------------- K2: FUSED {fwdT | wavefront | tvl1} ----------------
// blocks [0,1024): fwdT (needs y_img only)
// blocks [1024,1264): wavefront (needs sos <- k_mlp)
// blocks [1264,2288): tvl1 (needs sos <- k_mlp)
// Union LDS = fwdT's 18.4 KB (others tiny) -> no path pays extra (R6 lesson).
__global__ __launch_bounds__(256) void k_mid(
    const float* __restrict__ y_img, float2* __restrict__ bufA,
    const float* __restrict__ sos, const float* __restrict__ xq_p,
    const float* __restrict__ yq_p, const float* __restrict__ x_vec,
    const float* __restrict__ y_vec, float* __restrict__ wfs,
    const float* __restrict__ mask, float* __restrict__ acc) {
  __shared__ float2 s[4][RSW];
  int bid = blockIdx.x;
  int tid = threadIdx.x;
  if (bid < 1024) {
    // ---------- fwdT: real-pair packed v-axis FFT, Hermitian store ----------
    int rt = bid & 31;
    int d = bid >> 5;
    const float INV2S2 = (float)(0.6931471805599453 / 1406.25);
    for (int e = tid; e < 2048; e += 256) {
      int i = e >> 8, c = e & 255;
      int r = rt * 8 + i;
      float axr = (float)r - 127.5f;
      float axc = (float)c - 127.5f;
      float g = __expf(-(axr * axr + axc * axc) * INV2S2);
      float val = y_img[((size_t)d << 16) + (r << 8) + c] * g;
      int p = i >> 1, comp = i & 1;
      ((float*)&s[p][PHY(brev9((c + 384) & 511))])[comp] = val;
      ((float*)&s[p][PHY(brev9(c + 128))])[comp] = 0.f;
    }
    __syncthreads();
    fft512_r4_fwd_rows4(s, tid);
    float2* outp = bufA + ((size_t)d << 17) + rt * 8;
    for (int e = tid; e < 2056; e += 256) {
      int i = e & 7, v = e >> 3;
      int p = i >> 1, comp = i & 1;
      float2 Zv = s[p][PHY(v)];
      float2 Zm = s[p][PHY((512 - v) & 511)];
      float2 Yv;
      if (comp == 0) Yv = make_float2(0.5f * (Zv.x + Zm.x), 0.5f * (Zv.y - Zm.y));
      else           Yv = make_float2(0.5f * (Zv.y + Zm.y), 0.5f * (Zm.x - Zv.x));
      outp[(size_t)v * 256 + i] = Yv;
    }
  } else if (bid < 1024 + NTH) {
    // ---------- wavefront ray integral ----------
    int i = bid - 1024;
    int j = tid;
    float xq = xq_p[0], yq = yq_p[0];
    float r = sqrtf(xq * xq + yq * yq);
    float phi = atan2f(xq, yq);
    float th = (float)((double)i * (2.0 * M_PI / 239.0));
    float sn = sinf(th - phi), cd = cosf(th - phi);
    const float R2 = 0.008f * 0.008f;
    float disc = fmaxf(R2 - (r * sn) * (r * sn), 0.f);
    float sq = sqrtf(disc);
    float l_in = sq + r * cd;
    float l_out = 2.f * sq * (cd >= 0.f ? 1.f : 0.f);
    float l = (r < 0.008f) ? l_in : l_out;
    float x0 = x_vec[0], dx = x_vec[1] - x_vec[0];
    float y0 = y_vec[0], dy = y_vec[1] - y_vec[0];
    float sinth = sinf(th), costh = cosf(th);
    float contrib = 0.f;
    if (j < NINT) {
      float sj = (float)j * (1.f / 249.f);
      int xi = (int)rintf((xq - l * sj * sinth - x0) / dx);
      int yi = (int)rintf((yq - l * sj * costh - y0) / dy);
      float sv = sos[(((-yi) & 511) << 9) + (xi & 511)];
      float f = 1.f - 1500.f / sv;
      float wgt = (j == 0 || j == NINT - 1) ? 0.5f : 1.f;
      contrib = wgt * f;
    }
    float tot = block_reduce_any(contrib);
    if (tid == 0) wfs[i] = tot * l * (1.f / 249.f);
  } else {
    // ---------- tvl1 ----------
    int t = (bid - 1024 - NTH) * 256 + tid;
    float sv = sos[t];
    float m = mask[t];
    int i = t >> 9, j = t & 511;
    float tv = 0.f;
    if (i > 0) tv += fabsf((sv - sos[t - 512]) * m);
    if (j > 0) tv += fabsf((sv - sos[t - 1]) * m);
    float l1 = fabsf(sv - 1550.f) * m;
    float tvb = block_reduce_any(tv);
    float l1b = block_reduce_any(l1);
    if (tid == 0) {
      atomicAdd(&acc[1], tvb);
      atomicAdd(&acc[2], l1b);
    }
  }
}

// ---------------- K3: u-axis FFT + deconv + loss + u-axis ifft of X --------
// Hermitian-halved: grid = 257 v-blocks; loss weight 2 for v in [1,255];
// mirror store X(512-v) = conj(X(v)) after the u-ifft.
__device__ __forceinline__ float interp_wf(const float* wfs, float xn) {
  const float dxg = (float)(2.0 * M_PI / 239.0);
  float t = xn / dxg;
  int f = (int)floorf(t); f = min(max(f, 0), 239);
  int c = (int)ceilf(t);  c = min(max(c, 0), 239);
  float yf = wfs[f], yc = wfs[c];
  if (c == f) return yc;
  float xgf = (float)f * dxg;
  return yf + (yc - yf) * (xn - xgf) / ((float)(c - f) * dxg);
}

__global__ __launch_bounds__(256) void k_colfft_deconv(
    const float2* __restrict__ bufA, const float* __restrict__ delays,
    const float* __restrict__ wfs_g, float2* __restrict__ Xo,
    float* __restrict__ acc) {
  __shared__ float2 s[8][RSW];
  __shared__ float wfs[NTH];
  __shared__ float dly[NDEL];
  int v = blockIdx.x;            // 0..256
  int tid = threadIdx.x;
  if (tid < NTH) wfs[tid] = wfs_g[tid];
  if (tid < NDEL) dly[tid] = delays[tid];
  __syncthreads();

  const float inv_nd = 1.f / 0.02048f;
  const float TWO_PI = 6.28318530717958647692f;
  float fy = (float)(v < 256 ? v : v - 512) * inv_nd;
  float kkA[2];
  float2 zw[2], zwpi[2];   // exp(i kk w), exp(i kk wpi)
  int up[2];
  #pragma unroll
  for (int uu = 0; uu < 2; ++uu) {
    int u = tid + 256 * uu;
    up[uu] = PHY(u);
    float fx = (float)(u < 256 ? u : u - 512) * inv_nd;
    float kk = TWO_PI * sqrtf(fx * fx + fy * fy);
    kkA[uu] = kk;
    float th = atan2f(fy, fx);
    if (th < 0.f) th += TWO_PI;
    float w = interp_wf(wfs, th);
    float thpi = th + PI_F;
    if (thpi >= TWO_PI) thpi -= TWO_PI;
    float wpi = interp_wf(wfs, thpi);
    float snw, csw; __sincosf(kk * w, &snw, &csw);
    zw[uu] = make_float2(csw, snw);
    float snp, csp; __sincosf(kk * wpi, &snp, &csp);
    zwpi[uu] = make_float2(csp, snp);
  }

  float rhsr[2] = {0.f, 0.f}, rhsi[2] = {0.f, 0.f}, lhs[2] = {0.f, 0.f};
  float sY2[2] = {0.f, 0.f}, sYH[2] = {0.f, 0.f};

  for (int c4 = 0; c4 < 4; ++c4) {
    __syncthreads();   // previous chunk's reads done
    for (int e = tid; e < 2048; e += 256) {
      int ch = e >> 8, c = e & 255;
      float2 val = bufA[((size_t)(c4 * 8 + ch) << 17) + (size_t)v * 256 + c];
      s[ch][PHY(brev9((c + 384) & 511))] = val;
      s[ch][PHY(brev9(c + 128))] = make_float2(0.f, 0.f);
    }
    __syncthreads();
    fft512_r4_fwd_rows(s, tid);
    #pragma unroll
    for (int uu = 0; uu < 2; ++uu) {
      float kk = kkA[uu];
      float2 w0 = zw[uu], w1 = zwpi[uu];
      #pragma unroll
      for (int ch = 0; ch < 8; ++ch) {
        float dl = dly[c4 * 8 + ch];
        float sd, cd2;
        __sincosf(kk * dl, &sd, &cd2);
        // H = 0.5*(conj(zd)*zw + zd*conj(zwpi)), zd = exp(i kk d)
        float t0r = cd2 * w0.x + sd * w0.y;
        float t0i = cd2 * w0.y - sd * w0.x;
        float t1r = cd2 * w1.x + sd * w1.y;
        float t1i = sd * w1.x - cd2 * w1.y;
        float Hr = 0.5f * (t0r + t1r);
        float Hi = 0.5f * (t0i + t1i);
        float2 Yv = s[ch][up[uu]];
        rhsr[uu] += Yv.x * Hr + Yv.y * Hi;
        rhsi[uu] += Yv.y * Hr - Yv.x * Hi;
        float h2 = Hr * Hr + Hi * Hi;
        float y2 = Yv.x * Yv.x + Yv.y * Yv.y;
        lhs[uu] += h2;
        sY2[uu] += y2;
        sYH[uu] += sqrtf(y2 * h2);
      }
    }
  }
  // finalize X (registers) + weighted loss (Hermitian doubling)
  float lw = (v == 0 || v == 256) ? 1.f : 2.f;
  float2 Xv[2];
  float lsum = 0.f;
  #pragma unroll
  for (int uu = 0; uu < 2; ++uu) {
    float Xr = rhsr[uu] / lhs[uu], Xi = rhsi[uu] / lhs[uu];
    Xv[uu] = make_float2(Xr, Xi);
    float aX = sqrtf(Xr * Xr + Xi * Xi);
    float kk2 = kkA[uu] * kkA[uu];
    lsum += kk2 * (sY2[uu] - 2.f * aX * sYH[uu] + aX * aX * lhs[uu]);
  }
  float bs = block_reduce_any(lsum * lw);
  if (threadIdx.x == 0) atomicAdd(&acc[0], bs);
  // fused u-axis inverse FFT of this v's X row (reuse LDS row 0)
  __syncthreads();
  float2* s0 = &s[0][0];
  s0[PHY(brev9(tid))] = Xv[0];
  s0[PHY(brev9(tid + 256))] = Xv[1];
  __syncthreads();
  fft512_r4_row(s0, tid, +1.f);
  const float sc = 1.f / 512.f;
  float2 o0 = s0[PHY(tid)], o1 = s0[PHY(tid + 256)];
  o0.x *= sc; o0.y *= sc; o1.x *= sc; o1.y *= sc;
  Xo[((size_t)v << 9) + tid] = o0;
  Xo[((size_t)v << 9) + tid + 256] = o1;
  if (v != 0 && v != 256) {
    int vm = 512 - v;
    Xo[((size_t)vm << 9) + tid] = make_float2(o0.x, -o0.y);
    Xo[((size_t)vm << 9) + tid + 256] = make_float2(o1.x, -o1.y);
  }
}

// ---------------- K4: in-place paired-tile transpose ----------------
__global__ __launch_bounds__(256) void k_transpose_ip(float2* __restrict__ B) {
  int ti = blockIdx.x, tj = blockIdx.y;
  if (ti > tj) return;
  __shared__ float2 At[32][33];
  __shared__ float2 Bt[32][33];
  int tid = threadIdx.x;
  for (int e = tid; e < 1024; e += 256) {
    int r = e >> 5, c = e & 31;
    At[r][c] = B[(size_t)(ti * 32 + r) * 512 + tj * 32 + c];
    if (ti != tj) Bt[r][c] = B[(size_t)(tj * 32 + r) * 512 + ti * 32 + c];
  }
  __syncthreads();
  for (int e = tid; e < 1024; e += 256) {
    int r = e >> 5, c = e & 31;
    B[(size_t)(tj * 32 + r) * 512 + ti * 32 + c] = At[c][r];
    if (ti != tj) B[(size_t)(ti * 32 + r) * 512 + tj * 32 + c] = Bt[c][r];
  }
}

// ---------------- K5: final inverse row FFT (radix-4) + fftshift store -----
// Also finalizes loss (block 0, thread 0) — colfft and tvl1 already done.
__global__ __launch_bounds__(256) void k_final_rows(const float2* __restrict__ buf,
                                                    float* __restrict__ xrec,
                                                    const float* __restrict__ acc,
                                                    float* __restrict__ lossout) {
  __shared__ float2 s[RSW];
  int arow = blockIdx.x;
  const float2* p = buf + ((size_t)arow << 9);
  int tid = threadIdx.x;
  if (arow == 0 && tid == 0)
    lossout[0] = acc[0] * (1.f / 8388608.f) + 1e-3f * acc[1] + 1e-3f * (acc[2] * (1.f / 262144.f));
  s[PHY(brev9(tid))] = p[tid];
  s[PHY(brev9(tid + 256))] = p[tid + 256];
  __syncthreads();
  fft512_r4_row(s, tid, +1.f);
  int orow = (arow + 256) & 511;
  const float sc = 1.f / 512.f;
  xrec[(orow << 9) + ((tid + 256) & 511)] = s[PHY(tid)].x * sc;
  xrec[(orow << 9) + (tid & 511)] = s[PHY(tid + 256)].x * sc;
}

// ---------------- launch ----------------
extern "C" void kernel_launch(void* const* d_in, const int* in_sizes, int n_in,
                              void* d_out, int out_size, void* d_ws, size_t ws_size,
                              hipStream_t stream) {
  const float* W1 = (const float*)d_in[0];
  const float* b1 = (const float*)d_in[1];
  const float* W2 = (const float*)d_in[2];
  const float* b2 = (const float*)d_in[3];
  const float* W3 = (const float*)d_in[4];
  const float* b3 = (const float*)d_in[5];
  const float* W4 = (const float*)d_in[6];
  const float* b4 = (const float*)d_in[7];
  const float* y_img = (const float*)d_in[8];
  const float* delays = (const float*)d_in[9];
  const float* xq = (const float*)d_in[10];
  const float* yq = (const float*)d_in[11];
  const float* mgrid = (const float*)d_in[12];
  const float* mask = (const float*)d_in[13];
  const int* mask_idx = (const int*)d_in[14];
  const float* x_vec = (const float*)d_in[15];
  const float* y_vec = (const float*)d_in[16];
  const int M = in_sizes[14];
  const int nMlp = (M + MLP_P - 1) / MLP_P;

  float* out = (float*)d_out;
  float* xrec = out;                    // 262144
  float* sos = out + SOS_ELEMS;         // 262144
  float* loss = out + 2 * SOS_ELEMS;    // 1

  char* wsb = (char*)d_ws;
  float* acc = (float*)wsb;                                     // 4 floats
  float* wfs = (float*)(wsb + 1024);                            // 240 floats
  float2* bufA = (float2*)(wsb + 4096);                         // 32ch x 131072 c64
  float2* bufX = (float2*)(wsb + 4096 + (size_t)NDEL * 512 * 256 * sizeof(float2)); // 2 MB

  k_mlp<<<nMlp, 128, 0, stream>>>(W1, b1, W2, b2, W3, b3, W4, b4,
                                  mgrid, mask_idx, mask, M, sos, acc);
  k_mid<<<1024 + NTH + 1024, 256, 0, stream>>>(y_img, bufA, sos, xq, yq,
                                               x_vec, y_vec, wfs, mask, acc);
  k_colfft_deconv<<<257, 256, 0, stream>>>(bufA, delays, wfs, bufX, acc); // Hermitian half
  k_transpose_ip<<<dim3(16, 16), 256, 0, stream>>>(bufX);
  k_final_rows<<<512, 256, 0, stream>>>(bufX, xrec, acc, loss);
}

// Round 19
// 206.009 us; speedup vs baseline: 1.2497x; 1.0180x over previous
//
#include <hip/hip_runtime.h>
#include <hip/hip_bf16.h>
#include <math.h>

// ---------------- constants ----------------
#define NP 512
#define NIMG 256
#define NDEL 32
#define NTH 240
#define NINT 250
#define SOS_ELEMS (512*512)
#define MLP_P 32
// swizzled physical index for FFT LDS rows
#define PHY(i) ((i) + ((i) >> 3))
#define RSW 576   // PHY(511)=574 -> row array size
#define PI_F 3.14159265358979323846f

__device__ __forceinline__ int brev9(int i) { return (int)(__brev((unsigned)i) >> 23); }

__device__ __forceinline__ float block_reduce_any(float v) {
  #pragma unroll
  for (int o = 32; o > 0; o >>= 1) v += __shfl_down(v, o, 64);
  __shared__ float red[8];
  int lane = threadIdx.x & 63, wid = threadIdx.x >> 6;
  __syncthreads();
  if (lane == 0) red[wid] = v;
  __syncthreads();
  float r = 0.f;
  if (threadIdx.x == 0) {
    int nw = blockDim.x >> 6;
    for (int i = 0; i < nw; ++i) r += red[i];
  }
  return r;
}

// ---- radix-4 FFT core butterfly (sign = -1 fwd, +1 inv) ----
__device__ __forceinline__ void r4_bfly(float2& x0, float2& x1, float2& x2, float2& x3,
                                        float c1, float s1n, float c2, float s2n, float sign) {
  float t1x = x1.x * c1 - x1.y * s1n, t1y = x1.x * s1n + x1.y * c1;
  float y0x = x0.x + t1x, y0y = x0.y + t1y;
  float y1x = x0.x - t1x, y1y = x0.y - t1y;
  float t3x = x3.x * c1 - x3.y * s1n, t3y = x3.x * s1n + x3.y * c1;
  float y2x = x2.x + t3x, y2y = x2.y + t3y;
  float y3x = x2.x - t3x, y3y = x2.y - t3y;
  float t2x = y2x * c2 - y2y * s2n, t2y = y2x * s2n + y2y * c2;
  float ux = y3x * c2 - y3y * s2n, uy = y3x * s2n + y3y * c2;
  float t4x = -sign * uy, t4y = sign * ux;   // rotate by sign*i (fwd: -i)
  x0 = make_float2(y0x + t2x, y0y + t2y);
  x2 = make_float2(y0x - t2x, y0y - t2y);
  x1 = make_float2(y1x + t4x, y1y + t4y);
  x3 = make_float2(y1x - t4x, y1y - t4y);
}

// radix-4 FFT, 512 pts x 8 rows, 256 threads, swizzled LDS, forward.
__device__ __forceinline__ void fft512_r4_fwd_rows(float2 (*s)[RSW], int tid) {
  #pragma unroll
  for (int pass = 0; pass < 4; ++pass) {
    const int sh = 2 * pass;
    const int h = 1 << sh;
    int p = tid & 127;
    int rbase = (tid >> 7) << 2;
    int j = p & (h - 1);
    int g = p >> sh;
    int base = (g << (sh + 2)) + j;
    int i0 = PHY(base), i1 = PHY(base + h), i2 = PHY(base + 2 * h), i3 = PHY(base + 3 * h);
    float ang1 = -PI_F * (float)j / (float)h;
    float s1n, c1; __sincosf(ang1, &s1n, &c1);
    float s2n, c2; __sincosf(0.5f * ang1, &s2n, &c2);
    #pragma unroll
    for (int rr = 0; rr < 4; ++rr) {
      int r = rbase + rr;
      float2 x0 = s[r][i0], x1 = s[r][i1], x2 = s[r][i2], x3 = s[r][i3];
      r4_bfly(x0, x1, x2, x3, c1, s1n, c2, s2n, -1.f);
      s[r][i0] = x0; s[r][i1] = x1; s[r][i2] = x2; s[r][i3] = x3;
    }
    __syncthreads();
  }
  {
    int p = tid;
    int i1 = PHY(p), i2 = PHY(p + 256);
    float ang = -PI_F * (float)p * (1.f / 256.f);
    float sn, cs; __sincosf(ang, &sn, &cs);
    #pragma unroll
    for (int r = 0; r < 8; ++r) {
      float2 a = s[r][i1], b = s[r][i2];
      float tr = b.x * cs - b.y * sn;
      float ti = b.x * sn + b.y * cs;
      s[r][i1] = make_float2(a.x + tr, a.y + ti);
      s[r][i2] = make_float2(a.x - tr, a.y - ti);
    }
    __syncthreads();
  }
}

// radix-4 FFT, 512 pts x 4 rows (packed real pairs), 256 threads.
__device__ __forceinline__ void fft512_r4_fwd_rows4(float2 (*s)[RSW], int tid) {
  #pragma unroll
  for (int pass = 0; pass < 4; ++pass) {
    const int sh = 2 * pass;
    const int h = 1 << sh;
    int p = tid & 127;
    int rbase = (tid >> 7) << 1;
    int j = p & (h - 1);
    int g = p >> sh;
    int base = (g << (sh + 2)) + j;
    int i0 = PHY(base), i1 = PHY(base + h), i2 = PHY(base + 2 * h), i3 = PHY(base + 3 * h);
    float ang1 = -PI_F * (float)j / (float)h;
    float s1n, c1; __sincosf(ang1, &s1n, &c1);
    float s2n, c2; __sincosf(0.5f * ang1, &s2n, &c2);
    #pragma unroll
    for (int rr = 0; rr < 2; ++rr) {
      int r = rbase + rr;
      float2 x0 = s[r][i0], x1 = s[r][i1], x2 = s[r][i2], x3 = s[r][i3];
      r4_bfly(x0, x1, x2, x3, c1, s1n, c2, s2n, -1.f);
      s[r][i0] = x0; s[r][i1] = x1; s[r][i2] = x2; s[r][i3] = x3;
    }
    __syncthreads();
  }
  {
    int p = tid;
    int i1 = PHY(p), i2 = PHY(p + 256);
    float ang = -PI_F * (float)p * (1.f / 256.f);
    float sn, cs; __sincosf(ang, &sn, &cs);
    #pragma unroll
    for (int r = 0; r < 4; ++r) {
      float2 a = s[r][i1], b = s[r][i2];
      float tr = b.x * cs - b.y * sn;
      float ti = b.x * sn + b.y * cs;
      s[r][i1] = make_float2(a.x + tr, a.y + ti);
      s[r][i2] = make_float2(a.x - tr, a.y - ti);
    }
    __syncthreads();
  }
}

// radix-4 FFT, single 512-pt row, 256 threads, swizzled LDS, sign-param.
__device__ __forceinline__ void fft512_r4_row(float2* s, int tid, float sign) {
  #pragma unroll
  for (int pass = 0; pass < 4; ++pass) {
    const int sh = 2 * pass;
    const int h = 1 << sh;
    if (tid < 128) {
      int j = tid & (h - 1);
      int g = tid >> sh;
      int base = (g << (sh + 2)) + j;
      int i0 = PHY(base), i1 = PHY(base + h), i2 = PHY(base + 2 * h), i3 = PHY(base + 3 * h);
      float ang1 = sign * PI_F * (float)j / (float)h;
      float s1n, c1; __sincosf(ang1, &s1n, &c1);
      float s2n, c2; __sincosf(0.5f * ang1, &s2n, &c2);
      float2 x0 = s[i0], x1 = s[i1], x2 = s[i2], x3 = s[i3];
      r4_bfly(x0, x1, x2, x3, c1, s1n, c2, s2n, sign);
      s[i0] = x0; s[i1] = x1; s[i2] = x2; s[i3] = x3;
    }
    __syncthreads();
  }
  {
    int i1 = PHY(tid), i2 = PHY(tid + 256);
    float ang = sign * PI_F * (float)tid * (1.f / 256.f);
    float sn, cs; __sincosf(ang, &sn, &cs);
    float2 a = s[i1], b = s[i2];
    float tr = b.x * cs - b.y * sn;
    float ti = b.x * sn + b.y * cs;
    s[i1] = make_float2(a.x + tr, a.y + ti);
    s[i2] = make_float2(a.x - tr, a.y - ti);
    __syncthreads();
  }
}

// ---------------- K1: SIREN MLP + scatter + SoS background + acc zero ------
// 32 pts/block, 128 threads = 8 pg(4 pts) x 16 jg(8 j split {4jg, 64+4jg}).
// DO NOT retile: R10 split / R11 shrink / R15 16-row wbuf all regressed.
__global__ __launch_bounds__(128) void k_mlp(
    const float* __restrict__ W1, const float* __restrict__ b1,
    const float* __restrict__ W2, const float* __restrict__ b2,
    const float* __restrict__ W3, const float* __restrict__ b3,
    const float* __restrict__ W4v, const float* __restrict__ b4,
    const float* __restrict__ mgrid, const int* __restrict__ mask_idx,
    const float* __restrict__ mask, int M,
    float* __restrict__ sos, float* __restrict__ acc) {
  __shared__ float hbuf[MLP_P][132];
  __shared__ float wbuf[2][8][132];
  __shared__ float xy2[MLP_P][2];
  int tid = threadIdx.x;
  int base = blockIdx.x * MLP_P;
  if (tid < MLP_P * 2) {
    int p = tid >> 1, c = tid & 1;
    float v = 0.f;
    if (base + p < M) v = mgrid[(base + p) * 2 + c];
    xy2[p][c] = v;
  }
  if (blockIdx.x == 0 && tid < 4) acc[tid] = 0.f;
  for (int slab = blockIdx.x; slab < 1024; slab += gridDim.x) {
    #pragma unroll
    for (int e = 0; e < 2; ++e) {
      int t = slab * 256 + tid + e * 128;
      if (mask[t] == 0.f) sos[t] = 1499.363f;
    }
  }
  __syncthreads();
  for (int e = tid; e < MLP_P * 128; e += 128) {
    int p = e >> 7, j = e & 127;
    hbuf[p][j] = __sinf(30.f * (xy2[p][0] * W1[j] + xy2[p][1] * W1[128 + j] + b1[j]));
  }
  __syncthreads();

  int jg = tid & 15, pg = tid >> 4;
  int jA = jg * 4, jB = 64 + jg * 4;
  int p0 = pg * 4;
  int wr = tid >> 4, wc = (tid & 15) << 3;
  #pragma unroll
  for (int layer = 0; layer < 2; ++layer) {
    const float* Wg = layer ? W3 : W2;
    const float* bb = layer ? b3 : b2;
    float acr[4][8];
    #pragma unroll
    for (int i = 0; i < 4; ++i)
      #pragma unroll
      for (int j = 0; j < 8; ++j) acr[i][j] = 0.f;

    float4 pre1 = *(const float4*)&Wg[wr * 128 + wc];
    float4 pre2 = *(const float4*)&Wg[wr * 128 + wc + 4];
    for (int c = 0; c < 16; ++c) {
      *(float4*)&wbuf[c & 1][wr][wc] = pre1;
      *(float4*)&wbuf[c & 1][wr][wc + 4] = pre2;
      __syncthreads();
      if (c < 15) {
        pre1 = *(const float4*)&Wg[((c + 1) * 8 + wr) * 128 + wc];
        pre2 = *(const float4*)&Wg[((c + 1) * 8 + wr) * 128 + wc + 4];
      }
      int k0 = c * 8;
      float hreg[4][8];
      #pragma unroll
      for (int i = 0; i < 4; ++i) {
        float4 ha = *(const float4*)&hbuf[p0 + i][k0];
        float4 hb = *(const float4*)&hbuf[p0 + i][k0 + 4];
        hreg[i][0] = ha.x; hreg[i][1] = ha.y; hreg[i][2] = ha.z; hreg[i][3] = ha.w;
        hreg[i][4] = hb.x; hreg[i][5] = hb.y; hreg[i][6] = hb.z; hreg[i][7] = hb.w;
      }
      #pragma unroll
      for (int kk = 0; kk < 8; ++kk) {
        float4 wa = *(const float4*)&wbuf[c & 1][kk][jA];
        float4 wb = *(const float4*)&wbuf[c & 1][kk][jB];
        float w8[8] = {wa.x, wa.y, wa.z, wa.w, wb.x, wb.y, wb.z, wb.w};
        #pragma unroll
        for (int i = 0; i < 4; ++i) {
          float hv = hreg[i][kk];
          #pragma unroll
          for (int j = 0; j < 8; ++j) acr[i][j] += hv * w8[j];
        }
      }
    }
    float breg[8];
    #pragma unroll
    for (int j = 0; j < 4; ++j) { breg[j] = bb[jA + j]; breg[4 + j] = bb[jB + j]; }
    __syncthreads();
    #pragma unroll
    for (int i = 0; i < 4; ++i) {
      float o[8];
      #pragma unroll
      for (int j = 0; j < 8; ++j) o[j] = __sinf(30.f * (acr[i][j] + breg[j]));
      *(float4*)&hbuf[p0 + i][jA] = make_float4(o[0], o[1], o[2], o[3]);
      *(float4*)&hbuf[p0 + i][jB] = make_float4(o[4], o[5], o[6], o[7]);
    }
    __syncthreads();
  }
  {
    int p = tid >> 2, q = tid & 3;
    float s = 0.f;
    #pragma unroll
    for (int k = 0; k < 32; k += 4) {
      float4 h4 = *(const float4*)&hbuf[p][q * 32 + k];
      float4 w4 = *(const float4*)&W4v[q * 32 + k];
      s += h4.x * w4.x + h4.y * w4.y + h4.z * w4.z + h4.w * w4.w;
    }
    s += __shfl_down(s, 1, 64);
    s += __shfl_down(s, 2, 64);
    if (q == 0 && base + p < M)
      sos[mask_idx[base + p]] = (s + b4[0]) * 170.f + 1550.f;
  }
}

// ---------------- K2: FUSED {fwdT | wavefront | tvl1} ----------------
__global__ __launch_bounds__(256) void k_mid(
    const float* __restrict__ y_img, float2* __restrict__ bufA,
    const float* __restrict__ sos, const float* __restrict__ xq_p,
    const float* __restrict__ yq_p, const float* __restrict__ x_vec,
    const float* __restrict__ y_vec, float* __restrict__ wfs,
    const float* __restrict__ mask, float* __restrict__ acc) {
  __shared__ float2 s[4][RSW];
  int bid = blockIdx.x;
  int tid = threadIdx.x;
  if (bid < 1024) {
    // ---------- fwdT: real-pair packed v-axis FFT, Hermitian store ----------
    int rt = bid & 31;
    int d = bid >> 5;
    const float INV2S2 = (float)(0.6931471805599453 / 1406.25);
    for (int e = tid; e < 2048; e += 256) {
      int i = e >> 8, c = e & 255;
      int r = rt * 8 + i;
      float axr = (float)r - 127.5f;
      float axc = (float)c - 127.5f;
      float g = __expf(-(axr * axr + axc * axc) * INV2S2);
      float val = y_img[((size_t)d << 16) + (r << 8) + c] * g;
      int p = i >> 1, comp = i & 1;
      ((float*)&s[p][PHY(brev9((c + 384) & 511))])[comp] = val;
      ((float*)&s[p][PHY(brev9(c + 128))])[comp] = 0.f;
    }
    __syncthreads();
    fft512_r4_fwd_rows4(s, tid);
    float2* outp = bufA + ((size_t)d << 17) + rt * 8;
    for (int e = tid; e < 2056; e += 256) {
      int i = e & 7, v = e >> 3;
      int p = i >> 1, comp = i & 1;
      float2 Zv = s[p][PHY(v)];
      float2 Zm = s[p][PHY((512 - v) & 511)];
      float2 Yv;
      if (comp == 0) Yv = make_float2(0.5f * (Zv.x + Zm.x), 0.5f * (Zv.y - Zm.y));
      else           Yv = make_float2(0.5f * (Zv.y + Zm.y), 0.5f * (Zm.x - Zv.x));
      outp[(size_t)v * 256 + i] = Yv;
    }
  } else if (bid < 1024 + NTH) {
    // ---------- wavefront ray integral ----------
    int i = bid - 1024;
    int j = tid;
    float xq = xq_p[0], yq = yq_p[0];
    float r = sqrtf(xq * xq + yq * yq);
    float phi = atan2f(xq, yq);
    float th = (float)((double)i * (2.0 * M_PI / 239.0));
    float sn = sinf(th - phi), cd = cosf(th - phi);
    const float R2 = 0.008f * 0.008f;
    float disc = fmaxf(R2 - (r * sn) * (r * sn), 0.f);
    float sq = sqrtf(disc);
    float l_in = sq + r * cd;
    float l_out = 2.f * sq * (cd >= 0.f ? 1.f : 0.f);
    float l = (r < 0.008f) ? l_in : l_out;
    float x0 = x_vec[0], dx = x_vec[1] - x_vec[0];
    float y0 = y_vec[0], dy = y_vec[1] - y_vec[0];
    float sinth = sinf(th), costh = cosf(th);
    float contrib = 0.f;
    if (j < NINT) {
      float sj = (float)j * (1.f / 249.f);
      int xi = (int)rintf((xq - l * sj * sinth - x0) / dx);
      int yi = (int)rintf((yq - l * sj * costh - y0) / dy);
      float sv = sos[(((-yi) & 511) << 9) + (xi & 511)];
      float f = 1.f - 1500.f / sv;
      float wgt = (j == 0 || j == NINT - 1) ? 0.5f : 1.f;
      contrib = wgt * f;
    }
    float tot = block_reduce_any(contrib);
    if (tid == 0) wfs[i] = tot * l * (1.f / 249.f);
  } else {
    // ---------- tvl1 ----------
    int t = (bid - 1024 - NTH) * 256 + tid;
    float sv = sos[t];
    float m = mask[t];
    int i = t >> 9, j = t & 511;
    float tv = 0.f;
    if (i > 0) tv += fabsf((sv - sos[t - 512]) * m);
    if (j > 0) tv += fabsf((sv - sos[t - 1]) * m);
    float l1 = fabsf(sv - 1550.f) * m;
    float tvb = block_reduce_any(tv);
    float l1b = block_reduce_any(l1);
    if (tid == 0) {
      atomicAdd(&acc[1], tvb);
      atomicAdd(&acc[2], l1b);
    }
  }
}

// ---------------- K3: u-axis FFT + deconv + loss + u-ifft, TRANSPOSED store
// Hermitian-halved: grid = 257 v-blocks; loss weight 2 for v in [1,255];
// Stores Xo[u][v] (and mirror Xo[u][512-v]=conj) directly — no transpose kernel.
__device__ __forceinline__ float interp_wf(const float* wfs, float xn) {
  const float dxg = (float)(2.0 * M_PI / 239.0);
  float t = xn / dxg;
  int f = (int)floorf(t); f = min(max(f, 0), 239);
  int c = (int)ceilf(t);  c = min(max(c, 0), 239);
  float yf = wfs[f], yc = wfs[c];
  if (c == f) return yc;
  float xgf = (float)f * dxg;
  return yf + (yc - yf) * (xn - xgf) / ((float)(c - f) * dxg);
}

__global__ __launch_bounds__(256) void k_colfft_deconv(
    const float2* __restrict__ bufA, const float* __restrict__ delays,
    const float* __restrict__ wfs_g, float2* __restrict__ Xo,
    float* __restrict__ acc) {
  __shared__ float2 s[8][RSW];
  __shared__ float wfs[NTH];
  __shared__ float dly[NDEL];
  int v = blockIdx.x;            // 0..256
  int tid = threadIdx.x;
  if (tid < NTH) wfs[tid] = wfs_g[tid];
  if (tid < NDEL) dly[tid] = delays[tid];
  __syncthreads();

  const float inv_nd = 1.f / 0.02048f;
  const float TWO_PI = 6.28318530717958647692f;
  float fy = (float)(v < 256 ? v : v - 512) * inv_nd;
  float kkA[2];
  float2 zw[2], zwpi[2];   // exp(i kk w), exp(i kk wpi)
  int up[2];
  #pragma unroll
  for (int uu = 0; uu < 2; ++uu) {
    int u = tid + 256 * uu;
    up[uu] = PHY(u);
    float fx = (float)(u < 256 ? u : u - 512) * inv_nd;
    float kk = TWO_PI * sqrtf(fx * fx + fy * fy);
    kkA[uu] = kk;
    float th = atan2f(fy, fx);
    if (th < 0.f) th += TWO_PI;
    float w = interp_wf(wfs, th);
    float thpi = th + PI_F;
    if (thpi >= TWO_PI) thpi -= TWO_PI;
    float wpi = interp_wf(wfs, thpi);
    float snw, csw; __sincosf(kk * w, &snw, &csw);
    zw[uu] = make_float2(csw, snw);
    float snp, csp; __sincosf(kk * wpi, &snp, &csp);
    zwpi[uu] = make_float2(csp, snp);
  }

  float rhsr[2] = {0.f, 0.f}, rhsi[2] = {0.f, 0.f}, lhs[2] = {0.f, 0.f};
  float sY2[2] = {0.f, 0.f}, sYH[2] = {0.f, 0.f};

  for (int c4 = 0; c4 < 4; ++c4) {
    __syncthreads();   // previous chunk's reads done
    for (int e = tid; e < 2048; e += 256) {
      int ch = e >> 8, c = e & 255;
      float2 val = bufA[((size_t)(c4 * 8 + ch) << 17) + (size_t)v * 256 + c];
      s[ch][PHY(brev9((c + 384) & 511))] = val;
      s[ch][PHY(brev9(c + 128))] = make_float2(0.f, 0.f);
    }
    __syncthreads();
    fft512_r4_fwd_rows(s, tid);
    #pragma unroll
    for (int uu = 0; uu < 2; ++uu) {
      float kk = kkA[uu];
      float2 w0 = zw[uu], w1 = zwpi[uu];
      #pragma unroll
      for (int ch = 0; ch < 8; ++ch) {
        float dl = dly[c4 * 8 + ch];
        float sd, cd2;
        __sincosf(kk * dl, &sd, &cd2);
        // H = 0.5*(conj(zd)*zw + zd*conj(zwpi)), zd = exp(i kk d)
        float t0r = cd2 * w0.x + sd * w0.y;
        float t0i = cd2 * w0.y - sd * w0.x;
        float t1r = cd2 * w1.x + sd * w1.y;
        float t1i = sd * w1.x - cd2 * w1.y;
        float Hr = 0.5f * (t0r + t1r);
        float Hi = 0.5f * (t0i + t1i);
        float2 Yv = s[ch][up[uu]];
        rhsr[uu] += Yv.x * Hr + Yv.y * Hi;
        rhsi[uu] += Yv.y * Hr - Yv.x * Hi;
        float h2 = Hr * Hr + Hi * Hi;
        float y2 = Yv.x * Yv.x + Yv.y * Yv.y;
        lhs[uu] += h2;
        sY2[uu] += y2;
        sYH[uu] += sqrtf(y2 * h2);
      }
    }
  }
  // finalize X (registers) + weighted loss (Hermitian doubling)
  float lw = (v == 0 || v == 256) ? 1.f : 2.f;
  float2 Xv[2];
  float lsum = 0.f;
  #pragma unroll
  for (int uu = 0; uu < 2; ++uu) {
    float Xr = rhsr[uu] / lhs[uu], Xi = rhsi[uu] / lhs[uu];
    Xv[uu] = make_float2(Xr, Xi);
    float aX = sqrtf(Xr * Xr + Xi * Xi);
    float kk2 = kkA[uu] * kkA[uu];
    lsum += kk2 * (sY2[uu] - 2.f * aX * sYH[uu] + aX * aX * lhs[uu]);
  }
  float bs = block_reduce_any(lsum * lw);
  if (threadIdx.x == 0) atomicAdd(&acc[0], bs);
  // fused u-axis inverse FFT of this v's X row (reuse LDS row 0)
  __syncthreads();
  float2* s0 = &s[0][0];
  s0[PHY(brev9(tid))] = Xv[0];
  s0[PHY(brev9(tid + 256))] = Xv[1];
  __syncthreads();
  fft512_r4_row(s0, tid, +1.f);
  const float sc = 1.f / 512.f;
  float2 o0 = s0[PHY(tid)], o1 = s0[PHY(tid + 256)];
  o0.x *= sc; o0.y *= sc; o1.x *= sc; o1.y *= sc;
  // transposed store: Xo[u][v]
  Xo[((size_t)tid << 9) + v] = o0;
  Xo[((size_t)(tid + 256) << 9) + v] = o1;
  if (v != 0 && v != 256) {
    int vm = 512 - v;
    Xo[((size_t)tid << 9) + vm] = make_float2(o0.x, -o0.y);
    Xo[((size_t)(tid + 256) << 9) + vm] = make_float2(o1.x, -o1.y);
  }
}

// ---------------- K4: final inverse row FFT (radix-4) + fftshift store -----
// Also finalizes loss (block 0, thread 0) — colfft and tvl1 already done.
__global__ __launch_bounds__(256) void k_final_rows(const float2* __restrict__ buf,
                                                    float* __restrict__ xrec,
                                                    const float* __restrict__ acc,
                                                    float* __restrict__ lossout) {
  __shared__ float2 s[RSW];
  int arow = blockIdx.x;
  const float2* p = buf + ((size_t)arow << 9);
  int tid = threadIdx.x;
  if (arow == 0 && tid == 0)
    lossout[0] = acc[0] * (1.f / 8388608.f) + 1e-3f * acc[1] + 1e-3f * (acc[2] * (1.f / 262144.f));
  s[PHY(brev9(tid))] = p[tid];
  s[PHY(brev9(tid + 256))] = p[tid + 256];
  __syncthreads();
  fft512_r4_row(s, tid, +1.f);
  int orow = (arow + 256) & 511;
  const float sc = 1.f / 512.f;
  xrec[(orow << 9) + ((tid + 256) & 511)] = s[PHY(tid)].x * sc;
  xrec[(orow << 9) + (tid & 511)] = s[PHY(tid + 256)].x * sc;
}

// ---------------- launch ----------------
extern "C" void kernel_launch(void* const* d_in, const int* in_sizes, int n_in,
                              void* d_out, int out_size, void* d_ws, size_t ws_size,
                              hipStream_t stream) {
  const float* W1 = (const float*)d_in[0];
  const float* b1 = (const float*)d_in[1];
  const float* W2 = (const float*)d_in[2];
  const float* b2 = (const float*)d_in[3];
  const float* W3 = (const float*)d_in[4];
  const float* b3 = (const float*)d_in[5];
  const float* W4 = (const float*)d_in[6];
  const float* b4 = (const float*)d_in[7];
  const float* y_img = (const float*)d_in[8];
  const float* delays = (const float*)d_in[9];
  const float* xq = (const float*)d_in[10];
  const float* yq = (const float*)d_in[11];
  const float* mgrid = (const float*)d_in[12];
  const float* mask = (const float*)d_in[13];
  const int* mask_idx = (const int*)d_in[14];
  const float* x_vec = (const float*)d_in[15];
  const float* y_vec = (const float*)d_in[16];
  const int M = in_sizes[14];
  const int nMlp = (M + MLP_P - 1) / MLP_P;

  float* out = (float*)d_out;
  float* xrec = out;                    // 262144
  float* sos = out + SOS_ELEMS;         // 262144
  float* loss = out + 2 * SOS_ELEMS;    // 1

  char* wsb = (char*)d_ws;
  float* acc = (float*)wsb;                                     // 4 floats
  float* wfs = (float*)(wsb + 1024);                            // 240 floats
  float2* bufA = (float2*)(wsb + 4096);                         // 32ch x 131072 c64
  float2* bufX = (float2*)(wsb + 4096 + (size_t)NDEL * 512 * 256 * sizeof(float2)); // 2 MB

  k_mlp<<<nMlp, 128, 0, stream>>>(W1, b1, W2, b2, W3, b3, W4, b4,
                                  mgrid, mask_idx, mask, M, sos, acc);
  k_mid<<<1024 + NTH + 1024, 256, 0, stream>>>(y_img, bufA, sos, xq, yq,
                                               x_vec, y_vec, wfs, mask, acc);
  k_colfft_deconv<<<257, 256, 0, stream>>>(bufA, delays, wfs, bufX, acc); // Hermitian half
  k_final_rows<<<512, 256, 0, stream>>>(bufX, xrec, acc, loss);
}